// Round 3
// baseline (384.776 us; speedup 1.0000x reference)
//
#include <hip/hip_runtime.h>
#include <hip/hip_bf16.h>

#define B_ 4
#define H_ 16
#define S_ 2048
#define D_ 64
#define QBLK 64
#define KBLK 64
#define LDW 72   // padded LDS row width (bf16 elems): 64 + 8

typedef __attribute__((ext_vector_type(8))) short short8;
typedef __attribute__((ext_vector_type(4))) float f32x4;

__device__ __forceinline__ unsigned short f2bf(float f) {
  union { float f; unsigned int u; } x; x.f = f;
  unsigned int u = x.u;
  unsigned int r = (u + 0x7FFFu + ((u >> 16) & 1u)) >> 16;
  return (unsigned short)r;
}

__device__ __forceinline__ float bf2f(unsigned short h) {
  union { unsigned int u; float f; } y; y.u = ((unsigned int)h) << 16;
  return y.f;
}

__global__ __launch_bounds__(256, 2)
void attn_fwd(const float* __restrict__ Q, const float* __restrict__ K,
              const float* __restrict__ V, float* __restrict__ O) {
  // K staged as hi+lo bf16 planes (double-bf16 QK^T); V transposed, hi only.
  __shared__ alignas(16) unsigned short Kh_lds[KBLK * LDW];
  __shared__ alignas(16) unsigned short Kl_lds[KBLK * LDW];
  __shared__ alignas(16) unsigned short Vt_lds[D_ * LDW];
  __shared__ alignas(16) unsigned short P_lds[4][16 * LDW];

  const int tid  = threadIdx.x;
  const int lane = tid & 63;
  const int wid  = tid >> 6;
  const int l15  = lane & 15;
  const int dgrp = lane >> 4;

  const int qtile = blockIdx.x;
  const int bh    = blockIdx.y;

  const size_t base = (size_t)bh * S_ * D_;
  const float* Qb = Q + base;
  const float* Kb = K + base;
  const float* Vb = V + base;
  float*       Ob = O + base;

  const int qrow = qtile * QBLK + wid * 16 + l15;

  // ---- Q fragments (hi+lo) in registers: A[row=l15][k = s*32 + dgrp*8 + j] ----
  short8 qfh[2], qfl[2];
  {
    const float* qp = Qb + (size_t)qrow * D_ + dgrp * 8;
    #pragma unroll
    for (int s = 0; s < 2; ++s) {
      #pragma unroll
      for (int j = 0; j < 8; ++j) {
        float f = qp[s * 32 + j];
        unsigned short h = f2bf(f);
        qfh[s][j] = (short)h;
        qfl[s][j] = (short)f2bf(f - bf2f(h));
      }
    }
  }

  f32x4 oacc[4];
  #pragma unroll
  for (int t = 0; t < 4; ++t) oacc[t] = f32x4{0.f, 0.f, 0.f, 0.f};
  float m_r[4], l_r[4];
  #pragma unroll
  for (int j = 0; j < 4; ++j) { m_r[j] = -INFINITY; l_r[j] = 0.f; }

  for (int kb = 0; kb < S_; kb += KBLK) {
    __syncthreads();
    // ---- stage K (hi+lo bf16, row-major) and V (transposed bf16) ----
    #pragma unroll
    for (int c = 0; c < 4; ++c) {
      int e = (c * 256 + tid) * 4;     // element in 64x64 tile
      int r = e >> 6, col = e & 63;
      const float4 kv = *(const float4*)(Kb + (size_t)(kb + r) * D_ + col);
      ushort4 kh, kl;
      kh.x = f2bf(kv.x); kl.x = f2bf(kv.x - bf2f(kh.x));
      kh.y = f2bf(kv.y); kl.y = f2bf(kv.y - bf2f(kh.y));
      kh.z = f2bf(kv.z); kl.z = f2bf(kv.z - bf2f(kh.z));
      kh.w = f2bf(kv.w); kl.w = f2bf(kv.w - bf2f(kh.w));
      *(ushort4*)&Kh_lds[r * LDW + col] = kh;
      *(ushort4*)&Kl_lds[r * LDW + col] = kl;
      const float4 vv = *(const float4*)(Vb + (size_t)(kb + r) * D_ + col);
      Vt_lds[(col + 0) * LDW + r] = f2bf(vv.x);
      Vt_lds[(col + 1) * LDW + r] = f2bf(vv.y);
      Vt_lds[(col + 2) * LDW + r] = f2bf(vv.z);
      Vt_lds[(col + 3) * LDW + r] = f2bf(vv.w);
    }
    __syncthreads();

    // ---- QK^T (double-bf16): S = qh*kh + qh*kl + ql*kh ----
    f32x4 sa[4];
    #pragma unroll
    for (int t = 0; t < 4; ++t) {
      sa[t] = f32x4{0.f, 0.f, 0.f, 0.f};
      #pragma unroll
      for (int s = 0; s < 2; ++s) {
        const int off = (t * 16 + l15) * LDW + s * 32 + dgrp * 8;
        short8 kfh = *(const short8*)&Kh_lds[off];
        short8 kfl = *(const short8*)&Kl_lds[off];
        sa[t] = __builtin_amdgcn_mfma_f32_16x16x32_bf16(qfh[s], kfh, sa[t], 0, 0, 0);
        sa[t] = __builtin_amdgcn_mfma_f32_16x16x32_bf16(qfh[s], kfl, sa[t], 0, 0, 0);
        sa[t] = __builtin_amdgcn_mfma_f32_16x16x32_bf16(qfl[s], kfh, sa[t], 0, 0, 0);
      }
    }

    // ---- online softmax (rows: dgrp*4 + j; cols spread over 16 lanes x 4 tiles) ----
    float pmax[4];
    #pragma unroll
    for (int j = 0; j < 4; ++j) {
      float mx = fmaxf(fmaxf(sa[0][j], sa[1][j]), fmaxf(sa[2][j], sa[3][j]));
      #pragma unroll
      for (int m = 1; m < 16; m <<= 1) mx = fmaxf(mx, __shfl_xor(mx, m));
      pmax[j] = mx;
    }
    float scale[4];
    #pragma unroll
    for (int j = 0; j < 4; ++j) {
      float nm = fmaxf(m_r[j], pmax[j]);
      scale[j] = __expf(m_r[j] - nm);   // exp(-inf - finite) = 0 on first tile
      m_r[j] = nm;
    }
    float rs[4] = {0.f, 0.f, 0.f, 0.f};
    #pragma unroll
    for (int t = 0; t < 4; ++t) {
      #pragma unroll
      for (int j = 0; j < 4; ++j) {
        float p = __expf(sa[t][j] - m_r[j]);
        rs[j] += p;
        P_lds[wid][(dgrp * 4 + j) * LDW + t * 16 + l15] = f2bf(p);
      }
    }
    #pragma unroll
    for (int j = 0; j < 4; ++j) {
      #pragma unroll
      for (int m = 1; m < 16; m <<= 1) rs[j] += __shfl_xor(rs[j], m);
      l_r[j] = l_r[j] * scale[j] + rs[j];
      #pragma unroll
      for (int t = 0; t < 4; ++t) oacc[t][j] *= scale[j];
    }

    // ---- PV: O[16q x 64d] += P[16 x 64] * V[64 x 64] ----
    #pragma unroll
    for (int s = 0; s < 2; ++s) {
      short8 pf = *(const short8*)&P_lds[wid][l15 * LDW + s * 32 + dgrp * 8];
      #pragma unroll
      for (int t = 0; t < 4; ++t) {
        short8 vf = *(const short8*)&Vt_lds[(t * 16 + l15) * LDW + s * 32 + dgrp * 8];
        oacc[t] = __builtin_amdgcn_mfma_f32_16x16x32_bf16(pf, vf, oacc[t], 0, 0, 0);
      }
    }
  }

  // ---- epilogue: normalize and store fp32 ----
  #pragma unroll
  for (int j = 0; j < 4; ++j) {
    float inv = 1.0f / l_r[j];
    int row = qtile * QBLK + wid * 16 + dgrp * 4 + j;
    float* op = Ob + (size_t)row * D_ + l15;
    #pragma unroll
    for (int t = 0; t < 4; ++t)
      op[t * 16] = oacc[t][j] * inv;
  }
}

extern "C" void kernel_launch(void* const* d_in, const int* in_sizes, int n_in,
                              void* d_out, int out_size, void* d_ws, size_t ws_size,
                              hipStream_t stream) {
  const float* q = (const float*)d_in[0];
  const float* k = (const float*)d_in[1];
  const float* v = (const float*)d_in[2];
  float* o = (float*)d_out;
  dim3 grid(S_ / QBLK, B_ * H_);
  attn_fwd<<<grid, 256, 0, stream>>>(q, k, v, o);
}

// Round 4
// 273.779 us; speedup vs baseline: 1.4054x; 1.4054x over previous
//
#include <hip/hip_runtime.h>
#include <hip/hip_bf16.h>
#include <stdint.h>

#define B_ 4
#define H_ 16
#define S_ 2048
#define D_ 64
#define QBLK 64
#define KBLK 64
#define LDW 72   // fallback kernel only

typedef __attribute__((ext_vector_type(8))) short short8;
typedef __attribute__((ext_vector_type(4))) float f32x4;

__device__ __forceinline__ unsigned short f2bf(float f) {
  union { float f; unsigned int u; } x; x.f = f;
  unsigned int u = x.u;
  unsigned int r = (u + 0x7FFFu + ((u >> 16) & 1u)) >> 16;
  return (unsigned short)r;
}

__device__ __forceinline__ float bf2f(unsigned short h) {
  union { unsigned int u; float f; } y; y.u = ((unsigned int)h) << 16;
  return y.f;
}

#define GLOAD16(g, l) __builtin_amdgcn_global_load_lds( \
    (const __attribute__((address_space(1))) unsigned int*)(g), \
    (__attribute__((address_space(3))) unsigned int*)(l), 16, 0, 0)

// ---------- prep 1: K fp32 -> swizzled bf16 hi/lo planes ([S][128B] per bh) ----------
__global__ void prep_k(const float* __restrict__ K, unsigned short* __restrict__ Kh,
                       unsigned short* __restrict__ Kl) {
  int e4 = (blockIdx.x * 256 + threadIdx.x) * 4;   // element index (4 per thread)
  int bh  = e4 >> 17;          // / (S*D) = 131072
  int rem = e4 & 131071;
  int s   = rem >> 6;
  int d0  = rem & 63;          // multiple of 4
  const float4 kv = *(const float4*)(K + (size_t)e4);
  ushort4 h, l;
  h.x = f2bf(kv.x); l.x = f2bf(kv.x - bf2f(h.x));
  h.y = f2bf(kv.y); l.y = f2bf(kv.y - bf2f(h.y));
  h.z = f2bf(kv.z); l.z = f2bf(kv.z - bf2f(h.z));
  h.w = f2bf(kv.w); l.w = f2bf(kv.w - bf2f(h.w));
  size_t off = ((size_t)bh * S_ + s) * 128 + (unsigned)((d0 * 2) ^ ((s & 7) << 4));
  *(ushort4*)((char*)Kh + off) = h;
  *(ushort4*)((char*)Kl + off) = l;
}

// ---------- prep 2: V fp32 -> swizzled bf16 V^T plane ([64 d][S] per bh) ----------
__global__ void prep_v(const float* __restrict__ V, unsigned short* __restrict__ Vt) {
  __shared__ unsigned short tile[64][68];
  int bh = blockIdx.x >> 5;
  int st = blockIdx.x & 31;                     // s-tile of 64
  const float* Vb = V + ((size_t)bh * S_ + st * 64) * 64;
  int tid = threadIdx.x;
  #pragma unroll
  for (int i = 0; i < 4; ++i) {
    int idx = i * 1024 + tid * 4;
    int r = idx >> 6, c = idx & 63;
    float4 vv = *(const float4*)(Vb + (size_t)r * 64 + c);
    ushort4 o;
    o.x = f2bf(vv.x); o.y = f2bf(vv.y); o.z = f2bf(vv.z); o.w = f2bf(vv.w);
    *(ushort4*)&tile[r][c] = o;
  }
  __syncthreads();
  int chunk = tid & 15;        // s-chunk of 4 within tile
  int dbase = tid >> 4;        // 0..15
  size_t outb = (size_t)bh * (64 * S_ * 2) + (size_t)st * 128;
  #pragma unroll
  for (int i = 0; i < 4; ++i) {
    int d = dbase + i * 16;
    ushort4 o;
    o.x = tile[chunk * 4 + 0][d];
    o.y = tile[chunk * 4 + 1][d];
    o.z = tile[chunk * 4 + 2][d];
    o.w = tile[chunk * 4 + 3][d];
    size_t off = outb + (size_t)d * (S_ * 2) + (unsigned)((chunk * 8) ^ ((d & 7) << 4));
    *(ushort4*)((char*)Vt + off) = o;
  }
}

// ---------- main kernel: gload_lds staging + swizzled conflict-free LDS ----------
__global__ __launch_bounds__(256, 2)
void attn_fwd2(const float* __restrict__ Q, const unsigned short* __restrict__ Khg,
               const unsigned short* __restrict__ Klg, const unsigned short* __restrict__ Vtg,
               float* __restrict__ O) {
  __shared__ char smem[32768];
  char* Kh_l = smem;              // [64][128B]
  char* Kl_l = smem + 8192;
  char* Vt_l = smem + 16384;      // [64 d][128B]
  char* P_l  = smem + 24576;      // 4 waves x [16][128B]

  const int tid  = threadIdx.x;
  const int lane = tid & 63;
  const int wid  = tid >> 6;
  const int l15  = lane & 15;
  const int dgrp = lane >> 4;
  const int xsw  = (l15 & 7) << 4;

  const int qtile = blockIdx.x;
  const int bh    = blockIdx.y;

  const char* KhB = (const char*)Khg + (size_t)bh * (S_ * 128);
  const char* KlB = (const char*)Klg + (size_t)bh * (S_ * 128);
  const char* VtB = (const char*)Vtg + (size_t)bh * (64 * S_ * 2);
  const float* Qb = Q + (size_t)bh * S_ * D_;
  float*       Ob = O + (size_t)bh * S_ * D_;

  // ---- Q fragments (hi+lo): A[row=l15][k = s*32 + dgrp*8 + j] ----
  const int qrow = qtile * QBLK + wid * 16 + l15;
  short8 qfh[2], qfl[2];
  {
    const float* qp = Qb + (size_t)qrow * D_ + dgrp * 8;
    #pragma unroll
    for (int s = 0; s < 2; ++s) {
      #pragma unroll
      for (int j = 0; j < 8; ++j) {
        float f = qp[s * 32 + j];
        unsigned short h = f2bf(f);
        qfh[s][j] = (short)h;
        qfl[s][j] = (short)f2bf(f - bf2f(h));
      }
    }
  }

  f32x4 oacc[4];
  #pragma unroll
  for (int t = 0; t < 4; ++t) oacc[t] = f32x4{0.f, 0.f, 0.f, 0.f};
  float m_r[4], l_r[4];
  #pragma unroll
  for (int j = 0; j < 4; ++j) { m_r[j] = -INFINITY; l_r[j] = 0.f; }

  char* Pw = P_l + wid * 2048;

  for (int kb = 0; kb < S_; kb += KBLK) {
    __syncthreads();   // previous tile's LDS reads done
    // ---- stage via global_load_lds (1KB per wave-load; 24 loads, 6 per wave) ----
    #pragma unroll
    for (int c = 0; c < 6; ++c) {
      int id = c * 4 + wid;
      if (id < 8) {
        GLOAD16(KhB + (size_t)kb * 128 + id * 1024 + lane * 16, Kh_l + id * 1024);
      } else if (id < 16) {
        int i = id - 8;
        GLOAD16(KlB + (size_t)kb * 128 + i * 1024 + lane * 16, Kl_l + i * 1024);
      } else {
        int i = id - 16;
        GLOAD16(VtB + (size_t)(i * 8 + (lane >> 3)) * (S_ * 2) + ((kb >> 6) * 128) + (lane & 7) * 16,
                Vt_l + i * 1024);
      }
    }
    __syncthreads();   // drains vmcnt -> tile ready

    // ---- QK^T (double-bf16): S = qh*kh + qh*kl + ql*kh ----
    f32x4 sa[4];
    #pragma unroll
    for (int t = 0; t < 4; ++t) {
      sa[t] = f32x4{0.f, 0.f, 0.f, 0.f};
      #pragma unroll
      for (int s = 0; s < 2; ++s) {
        const int off = (t * 16 + l15) * 128 + ((s * 64 + dgrp * 16) ^ xsw);
        short8 kfh = *(const short8*)(Kh_l + off);
        short8 kfl = *(const short8*)(Kl_l + off);
        sa[t] = __builtin_amdgcn_mfma_f32_16x16x32_bf16(qfh[s], kfh, sa[t], 0, 0, 0);
        sa[t] = __builtin_amdgcn_mfma_f32_16x16x32_bf16(qfh[s], kfl, sa[t], 0, 0, 0);
        sa[t] = __builtin_amdgcn_mfma_f32_16x16x32_bf16(qfl[s], kfh, sa[t], 0, 0, 0);
      }
    }

    // ---- online softmax (rows dgrp*4+j; cols over 16 lanes x 4 tiles) ----
    float pmax[4];
    #pragma unroll
    for (int j = 0; j < 4; ++j) {
      float mx = fmaxf(fmaxf(sa[0][j], sa[1][j]), fmaxf(sa[2][j], sa[3][j]));
      #pragma unroll
      for (int m = 1; m < 16; m <<= 1) mx = fmaxf(mx, __shfl_xor(mx, m));
      pmax[j] = mx;
    }
    float scale[4];
    #pragma unroll
    for (int j = 0; j < 4; ++j) {
      float nm = fmaxf(m_r[j], pmax[j]);
      scale[j] = __expf(m_r[j] - nm);
      m_r[j] = nm;
    }
    float rs[4] = {0.f, 0.f, 0.f, 0.f};
    #pragma unroll
    for (int t = 0; t < 4; ++t) {
      #pragma unroll
      for (int j = 0; j < 4; ++j) {
        float p = __expf(sa[t][j] - m_r[j]);
        rs[j] += p;
        int prow = dgrp * 4 + j;
        *(unsigned short*)(Pw + prow * 128 + (((t * 16 + l15) * 2) ^ ((prow & 7) << 4))) = f2bf(p);
      }
    }
    #pragma unroll
    for (int j = 0; j < 4; ++j) {
      #pragma unroll
      for (int m = 1; m < 16; m <<= 1) rs[j] += __shfl_xor(rs[j], m);
      l_r[j] = l_r[j] * scale[j] + rs[j];
      #pragma unroll
      for (int t = 0; t < 4; ++t) oacc[t][j] *= scale[j];
    }

    // ---- PV: O[16q x 64d] += P[16 x 64] * V[64 x 64] ----
    #pragma unroll
    for (int s = 0; s < 2; ++s) {
      short8 pf = *(const short8*)(Pw + l15 * 128 + ((s * 64 + dgrp * 16) ^ xsw));
      #pragma unroll
      for (int t = 0; t < 4; ++t) {
        const int off = (t * 16 + l15) * 128 + ((s * 64 + dgrp * 16) ^ xsw);
        short8 vf = *(const short8*)(Vt_l + off);
        oacc[t] = __builtin_amdgcn_mfma_f32_16x16x32_bf16(pf, vf, oacc[t], 0, 0, 0);
      }
    }
  }

  // ---- epilogue ----
  #pragma unroll
  for (int j = 0; j < 4; ++j) {
    float inv = 1.0f / l_r[j];
    int row = qtile * QBLK + wid * 16 + dgrp * 4 + j;
    float* op = Ob + (size_t)row * D_ + l15;
    #pragma unroll
    for (int t = 0; t < 4; ++t)
      op[t * 16] = oacc[t][j] * inv;
  }
}

// ---------- fallback (round-3 kernel, used only if ws too small) ----------
__global__ __launch_bounds__(256, 2)
void attn_fwd(const float* __restrict__ Q, const float* __restrict__ K,
              const float* __restrict__ V, float* __restrict__ O) {
  __shared__ alignas(16) unsigned short Kh_lds[KBLK * LDW];
  __shared__ alignas(16) unsigned short Kl_lds[KBLK * LDW];
  __shared__ alignas(16) unsigned short Vt_lds[D_ * LDW];
  __shared__ alignas(16) unsigned short P_lds[4][16 * LDW];

  const int tid  = threadIdx.x;
  const int lane = tid & 63;
  const int wid  = tid >> 6;
  const int l15  = lane & 15;
  const int dgrp = lane >> 4;

  const int qtile = blockIdx.x;
  const int bh    = blockIdx.y;

  const size_t base = (size_t)bh * S_ * D_;
  const float* Qb = Q + base;
  const float* Kb = K + base;
  const float* Vb = V + base;
  float*       Ob = O + base;

  const int qrow = qtile * QBLK + wid * 16 + l15;
  short8 qfh[2], qfl[2];
  {
    const float* qp = Qb + (size_t)qrow * D_ + dgrp * 8;
    #pragma unroll
    for (int s = 0; s < 2; ++s)
      #pragma unroll
      for (int j = 0; j < 8; ++j) {
        float f = qp[s * 32 + j];
        unsigned short h = f2bf(f);
        qfh[s][j] = (short)h;
        qfl[s][j] = (short)f2bf(f - bf2f(h));
      }
  }

  f32x4 oacc[4];
  #pragma unroll
  for (int t = 0; t < 4; ++t) oacc[t] = f32x4{0.f, 0.f, 0.f, 0.f};
  float m_r[4], l_r[4];
  #pragma unroll
  for (int j = 0; j < 4; ++j) { m_r[j] = -INFINITY; l_r[j] = 0.f; }

  for (int kb = 0; kb < S_; kb += KBLK) {
    __syncthreads();
    #pragma unroll
    for (int c = 0; c < 4; ++c) {
      int e = (c * 256 + tid) * 4;
      int r = e >> 6, col = e & 63;
      const float4 kv = *(const float4*)(Kb + (size_t)(kb + r) * D_ + col);
      ushort4 kh, kl;
      kh.x = f2bf(kv.x); kl.x = f2bf(kv.x - bf2f(kh.x));
      kh.y = f2bf(kv.y); kl.y = f2bf(kv.y - bf2f(kh.y));
      kh.z = f2bf(kv.z); kl.z = f2bf(kv.z - bf2f(kh.z));
      kh.w = f2bf(kv.w); kl.w = f2bf(kv.w - bf2f(kh.w));
      *(ushort4*)&Kh_lds[r * LDW + col] = kh;
      *(ushort4*)&Kl_lds[r * LDW + col] = kl;
      const float4 vv = *(const float4*)(Vb + (size_t)(kb + r) * D_ + col);
      Vt_lds[(col + 0) * LDW + r] = f2bf(vv.x);
      Vt_lds[(col + 1) * LDW + r] = f2bf(vv.y);
      Vt_lds[(col + 2) * LDW + r] = f2bf(vv.z);
      Vt_lds[(col + 3) * LDW + r] = f2bf(vv.w);
    }
    __syncthreads();

    f32x4 sa[4];
    #pragma unroll
    for (int t = 0; t < 4; ++t) {
      sa[t] = f32x4{0.f, 0.f, 0.f, 0.f};
      #pragma unroll
      for (int s = 0; s < 2; ++s) {
        const int off = (t * 16 + l15) * LDW + s * 32 + dgrp * 8;
        short8 kfh = *(const short8*)&Kh_lds[off];
        short8 kfl = *(const short8*)&Kl_lds[off];
        sa[t] = __builtin_amdgcn_mfma_f32_16x16x32_bf16(qfh[s], kfh, sa[t], 0, 0, 0);
        sa[t] = __builtin_amdgcn_mfma_f32_16x16x32_bf16(qfh[s], kfl, sa[t], 0, 0, 0);
        sa[t] = __builtin_amdgcn_mfma_f32_16x16x32_bf16(qfl[s], kfh, sa[t], 0, 0, 0);
      }
    }

    float pmax[4];
    #pragma unroll
    for (int j = 0; j < 4; ++j) {
      float mx = fmaxf(fmaxf(sa[0][j], sa[1][j]), fmaxf(sa[2][j], sa[3][j]));
      #pragma unroll
      for (int m = 1; m < 16; m <<= 1) mx = fmaxf(mx, __shfl_xor(mx, m));
      pmax[j] = mx;
    }
    float scale[4];
    #pragma unroll
    for (int j = 0; j < 4; ++j) {
      float nm = fmaxf(m_r[j], pmax[j]);
      scale[j] = __expf(m_r[j] - nm);
      m_r[j] = nm;
    }
    float rs[4] = {0.f, 0.f, 0.f, 0.f};
    #pragma unroll
    for (int t = 0; t < 4; ++t)
      #pragma unroll
      for (int j = 0; j < 4; ++j) {
        float p = __expf(sa[t][j] - m_r[j]);
        rs[j] += p;
        P_lds[wid][(dgrp * 4 + j) * LDW + t * 16 + l15] = f2bf(p);
      }
    #pragma unroll
    for (int j = 0; j < 4; ++j) {
      #pragma unroll
      for (int m = 1; m < 16; m <<= 1) rs[j] += __shfl_xor(rs[j], m);
      l_r[j] = l_r[j] * scale[j] + rs[j];
      #pragma unroll
      for (int t = 0; t < 4; ++t) oacc[t][j] *= scale[j];
    }

    #pragma unroll
    for (int s = 0; s < 2; ++s) {
      short8 pf = *(const short8*)&P_lds[wid][l15 * LDW + s * 32 + dgrp * 8];
      #pragma unroll
      for (int t = 0; t < 4; ++t) {
        short8 vf = *(const short8*)&Vt_lds[(t * 16 + l15) * LDW + s * 32 + dgrp * 8];
        oacc[t] = __builtin_amdgcn_mfma_f32_16x16x32_bf16(pf, vf, oacc[t], 0, 0, 0);
      }
    }
  }

  #pragma unroll
  for (int j = 0; j < 4; ++j) {
    float inv = 1.0f / l_r[j];
    int row = qtile * QBLK + wid * 16 + dgrp * 4 + j;
    float* op = Ob + (size_t)row * D_ + l15;
    #pragma unroll
    for (int t = 0; t < 4; ++t)
      op[t * 16] = oacc[t][j] * inv;
  }
}

extern "C" void kernel_launch(void* const* d_in, const int* in_sizes, int n_in,
                              void* d_out, int out_size, void* d_ws, size_t ws_size,
                              hipStream_t stream) {
  const float* q = (const float*)d_in[0];
  const float* k = (const float*)d_in[1];
  const float* v = (const float*)d_in[2];
  float* o = (float*)d_out;
  const size_t PLANE = (size_t)B_ * H_ * S_ * 128;   // 16 MiB per bf16 plane
  if (ws_size >= 3 * PLANE) {
    unsigned short* Kh = (unsigned short*)d_ws;
    unsigned short* Kl = (unsigned short*)((char*)d_ws + PLANE);
    unsigned short* Vt = (unsigned short*)((char*)d_ws + 2 * PLANE);
    prep_k<<<8192, 256, 0, stream>>>(k, Kh, Kl);
    prep_v<<<2048, 256, 0, stream>>>(v, Vt);
    attn_fwd2<<<dim3(S_ / QBLK, B_ * H_), 256, 0, stream>>>(q, Kh, Kl, Vt, o);
  } else {
    attn_fwd<<<dim3(S_ / QBLK, B_ * H_), 256, 0, stream>>>(q, k, v, o);
  }
}

// Round 5
// 226.158 us; speedup vs baseline: 1.7014x; 1.2106x over previous
//
#include <hip/hip_runtime.h>
#include <hip/hip_bf16.h>
#include <stdint.h>

#define B_ 4
#define H_ 16
#define S_ 2048
#define D_ 64
#define QBLK 128
#define KBLK 64
#define LDW 72   // fallback kernel only

typedef __attribute__((ext_vector_type(8))) short short8;
typedef __attribute__((ext_vector_type(4))) float f32x4;
typedef _Float16 f16x8 __attribute__((ext_vector_type(8)));
typedef _Float16 f16x4 __attribute__((ext_vector_type(4)));

__device__ __forceinline__ unsigned short f2bf(float f) {
  union { float f; unsigned int u; } x; x.f = f;
  unsigned int u = x.u;
  unsigned int r = (u + 0x7FFFu + ((u >> 16) & 1u)) >> 16;
  return (unsigned short)r;
}

__device__ __forceinline__ float bf2f(unsigned short h) {
  union { unsigned int u; float f; } y; y.u = ((unsigned int)h) << 16;
  return y.f;
}

#define GLOAD16(g, l) __builtin_amdgcn_global_load_lds( \
    (const __attribute__((address_space(1))) unsigned int*)(g), \
    (__attribute__((address_space(3))) unsigned int*)(l), 16, 0, 0)

// ---------- prep 1: K fp32 -> swizzled fp16 plane ([S][128B] per bh) ----------
__global__ void prep_k(const float* __restrict__ K, _Float16* __restrict__ Kp) {
  int e4 = (blockIdx.x * 256 + threadIdx.x) * 4;   // element index (4 per thread)
  int bh  = e4 >> 17;          // / (S*D) = 131072
  int rem = e4 & 131071;
  int s   = rem >> 6;
  int d0  = rem & 63;          // multiple of 4
  const float4 kv = *(const float4*)(K + (size_t)e4);
  f16x4 h;
  h[0] = (_Float16)kv.x; h[1] = (_Float16)kv.y;
  h[2] = (_Float16)kv.z; h[3] = (_Float16)kv.w;
  size_t off = ((size_t)bh * S_ + s) * 128 + (unsigned)((d0 * 2) ^ ((s & 7) << 4));
  *(f16x4*)((char*)Kp + off) = h;
}

// ---------- prep 2: V fp32 -> swizzled fp16 V^T plane ([64 d][S] per bh) ----------
__global__ void prep_v(const float* __restrict__ V, _Float16* __restrict__ Vt) {
  __shared__ _Float16 tile[64][68];
  int bh = blockIdx.x >> 5;
  int st = blockIdx.x & 31;                     // s-tile of 64
  const float* Vb = V + ((size_t)bh * S_ + st * 64) * 64;
  int tid = threadIdx.x;
  #pragma unroll
  for (int i = 0; i < 4; ++i) {
    int idx = i * 1024 + tid * 4;
    int r = idx >> 6, c = idx & 63;
    float4 vv = *(const float4*)(Vb + (size_t)r * 64 + c);
    f16x4 o;
    o[0] = (_Float16)vv.x; o[1] = (_Float16)vv.y;
    o[2] = (_Float16)vv.z; o[3] = (_Float16)vv.w;
    *(f16x4*)&tile[r][c] = o;
  }
  __syncthreads();
  int chunk = tid & 15;        // s-chunk of 4 within tile
  int dbase = tid >> 4;        // 0..15
  size_t outb = (size_t)bh * (64 * S_ * 2) + (size_t)st * 128;
  #pragma unroll
  for (int i = 0; i < 4; ++i) {
    int d = dbase + i * 16;
    f16x4 o;
    o[0] = tile[chunk * 4 + 0][d];
    o[1] = tile[chunk * 4 + 1][d];
    o[2] = tile[chunk * 4 + 2][d];
    o[3] = tile[chunk * 4 + 3][d];
    size_t off = outb + (size_t)d * (S_ * 2) + (unsigned)((chunk * 8) ^ ((d & 7) << 4));
    *(f16x4*)((char*)Vt + off) = o;
  }
}

// ---------- main: fp16 QK^T, QBLK=128, double-buffered prefetch ----------
__global__ __launch_bounds__(256)
void attn_fwd3(const float* __restrict__ Q, const _Float16* __restrict__ Kg,
               const _Float16* __restrict__ Vg, float* __restrict__ O) {
  // layout: buf0 K 8K | buf0 V 8K | buf1 K 8K | buf1 V 8K | P 16K
  __shared__ char smem[49152];

  const int tid  = threadIdx.x;
  const int lane = tid & 63;
  const int wid  = tid >> 6;
  const int l15  = lane & 15;
  const int dgrp = lane >> 4;
  const int xsw  = (l15 & 7) << 4;

  const int qtile = blockIdx.x;
  const int bh    = blockIdx.y;

  const char* KB = (const char*)Kg + (size_t)bh * (S_ * 128);
  const char* VB = (const char*)Vg + (size_t)bh * (64 * S_ * 2);
  const float* Qb = Q + (size_t)bh * S_ * D_;
  float*       Ob = O + (size_t)bh * S_ * D_;

  // ---- Q fragments fp16: qf[mi][s], A[row=l15][k = s*32 + dgrp*8 + j] ----
  f16x8 qf[2][2];
  #pragma unroll
  for (int mi = 0; mi < 2; ++mi) {
    const int qrow = qtile * QBLK + wid * 32 + mi * 16 + l15;
    const float* qp = Qb + (size_t)qrow * D_ + dgrp * 8;
    #pragma unroll
    for (int s = 0; s < 2; ++s) {
      float4 a = *(const float4*)(qp + s * 32);
      float4 b = *(const float4*)(qp + s * 32 + 4);
      qf[mi][s][0] = (_Float16)a.x; qf[mi][s][1] = (_Float16)a.y;
      qf[mi][s][2] = (_Float16)a.z; qf[mi][s][3] = (_Float16)a.w;
      qf[mi][s][4] = (_Float16)b.x; qf[mi][s][5] = (_Float16)b.y;
      qf[mi][s][6] = (_Float16)b.z; qf[mi][s][7] = (_Float16)b.w;
    }
  }

  f32x4 oacc[2][4];
  float m_r[2][4], l_r[2][4];
  #pragma unroll
  for (int mi = 0; mi < 2; ++mi) {
    #pragma unroll
    for (int t = 0; t < 4; ++t) oacc[mi][t] = f32x4{0.f, 0.f, 0.f, 0.f};
    #pragma unroll
    for (int j = 0; j < 4; ++j) { m_r[mi][j] = -INFINITY; l_r[mi][j] = 0.f; }
  }

  char* Pw = smem + 32768 + wid * 4096;   // 32 rows x 128B per wave

  // stage one 64-key tile (K 8KB + V 8KB) into buf: 16 wave-loads, 4/wave
  #define STAGE(buf, kb)                                                        \
    {                                                                           \
      char* Kl_ = smem + (buf) * 16384;                                         \
      char* Vl_ = Kl_ + 8192;                                                   \
      _Pragma("unroll")                                                         \
      for (int c = 0; c < 4; ++c) {                                             \
        int id = c * 4 + wid;                                                   \
        if (id < 8) {                                                           \
          GLOAD16(KB + (size_t)(kb) * 128 + id * 1024 + lane * 16,              \
                  Kl_ + id * 1024);                                             \
        } else {                                                                \
          int i = id - 8;                                                       \
          GLOAD16(VB + (size_t)(i * 8 + (lane >> 3)) * (S_ * 2)                 \
                     + ((kb) >> 6) * 128 + (lane & 7) * 16,                     \
                  Vl_ + i * 1024);                                              \
        }                                                                       \
      }                                                                         \
    }

  STAGE(0, 0);
  __syncthreads();   // vmcnt(0) drain + barrier: buf0 ready

  for (int it = 0; it < S_ / KBLK; ++it) {
    const int cur = it & 1;
    if (it < S_ / KBLK - 1) STAGE(cur ^ 1, (it + 1) * KBLK);  // prefetch overlaps compute

    const char* Kl = smem + cur * 16384;
    const char* Vl = Kl + 8192;

    // ---- QK^T fp16: sa[mi][t] over 32q x 64k ----
    f32x4 sa[2][4];
    #pragma unroll
    for (int t = 0; t < 4; ++t) {
      f16x8 kf[2];
      #pragma unroll
      for (int s = 0; s < 2; ++s)
        kf[s] = *(const f16x8*)(Kl + (t * 16 + l15) * 128 + ((s * 64 + dgrp * 16) ^ xsw));
      #pragma unroll
      for (int mi = 0; mi < 2; ++mi) {
        f32x4 acc = (t == 0) ? f32x4{0.f, 0.f, 0.f, 0.f} : sa[mi][t];
        acc = f32x4{0.f, 0.f, 0.f, 0.f};
        acc = __builtin_amdgcn_mfma_f32_16x16x32_f16(qf[mi][0], kf[0], acc, 0, 0, 0);
        acc = __builtin_amdgcn_mfma_f32_16x16x32_f16(qf[mi][1], kf[1], acc, 0, 0, 0);
        sa[mi][t] = acc;
      }
    }

    // ---- online softmax per m-subtile ----
    #pragma unroll
    for (int mi = 0; mi < 2; ++mi) {
      float pmax[4];
      #pragma unroll
      for (int j = 0; j < 4; ++j) {
        float mx = fmaxf(fmaxf(sa[mi][0][j], sa[mi][1][j]),
                         fmaxf(sa[mi][2][j], sa[mi][3][j]));
        #pragma unroll
        for (int m = 1; m < 16; m <<= 1) mx = fmaxf(mx, __shfl_xor(mx, m));
        pmax[j] = mx;
      }
      float scale[4];
      #pragma unroll
      for (int j = 0; j < 4; ++j) {
        float nm = fmaxf(m_r[mi][j], pmax[j]);
        scale[j] = __expf(m_r[mi][j] - nm);
        m_r[mi][j] = nm;
      }
      float rs[4] = {0.f, 0.f, 0.f, 0.f};
      #pragma unroll
      for (int t = 0; t < 4; ++t) {
        #pragma unroll
        for (int j = 0; j < 4; ++j) {
          float p = __expf(sa[mi][t][j] - m_r[mi][j]);
          rs[j] += p;
          int prow = mi * 16 + dgrp * 4 + j;
          *(_Float16*)(Pw + prow * 128 + (((t * 16 + l15) * 2) ^ ((prow & 7) << 4))) =
              (_Float16)p;
        }
      }
      #pragma unroll
      for (int j = 0; j < 4; ++j) {
        #pragma unroll
        for (int m = 1; m < 16; m <<= 1) rs[j] += __shfl_xor(rs[j], m);
        l_r[mi][j] = l_r[mi][j] * scale[j] + rs[j];
        #pragma unroll
        for (int t = 0; t < 4; ++t) oacc[mi][t][j] *= scale[j];
      }
    }

    // ---- PV: O[32q x 64d] += P[32 x 64] * V[64 x 64] ----
    #pragma unroll
    for (int s = 0; s < 2; ++s) {
      f16x8 pf[2];
      #pragma unroll
      for (int mi = 0; mi < 2; ++mi)
        pf[mi] = *(const f16x8*)(Pw + (mi * 16 + l15) * 128 + ((s * 64 + dgrp * 16) ^ xsw));
      #pragma unroll
      for (int t = 0; t < 4; ++t) {
        f16x8 vf = *(const f16x8*)(Vl + (t * 16 + l15) * 128 + ((s * 64 + dgrp * 16) ^ xsw));
        #pragma unroll
        for (int mi = 0; mi < 2; ++mi)
          oacc[mi][t] = __builtin_amdgcn_mfma_f32_16x16x32_f16(pf[mi], vf, oacc[mi][t], 0, 0, 0);
      }
    }
    __syncthreads();   // drains prefetch vmcnt + protects LDS reuse
  }

  // ---- epilogue ----
  #pragma unroll
  for (int mi = 0; mi < 2; ++mi) {
    #pragma unroll
    for (int j = 0; j < 4; ++j) {
      float inv = 1.0f / l_r[mi][j];
      int row = qtile * QBLK + wid * 32 + mi * 16 + dgrp * 4 + j;
      float* op = Ob + (size_t)row * D_ + l15;
      #pragma unroll
      for (int t = 0; t < 4; ++t)
        op[t * 16] = oacc[mi][t][j] * inv;
    }
  }
  #undef STAGE
}

// ---------- fallback (round-3 kernel, used only if ws too small) ----------
__global__ __launch_bounds__(256, 2)
void attn_fwd(const float* __restrict__ Q, const float* __restrict__ K,
              const float* __restrict__ V, float* __restrict__ O) {
  __shared__ alignas(16) unsigned short Kh_lds[KBLK * LDW];
  __shared__ alignas(16) unsigned short Kl_lds[KBLK * LDW];
  __shared__ alignas(16) unsigned short Vt_lds[D_ * LDW];
  __shared__ alignas(16) unsigned short P_lds[4][16 * LDW];

  const int tid  = threadIdx.x;
  const int lane = tid & 63;
  const int wid  = tid >> 6;
  const int l15  = lane & 15;
  const int dgrp = lane >> 4;

  const int qtile = blockIdx.x;
  const int bh    = blockIdx.y;

  const size_t base = (size_t)bh * S_ * D_;
  const float* Qb = Q + base;
  const float* Kb = K + base;
  const float* Vb = V + base;
  float*       Ob = O + base;

  const int qrow = qtile * 64 + wid * 16 + l15;
  short8 qfh[2], qfl[2];
  {
    const float* qp = Qb + (size_t)qrow * D_ + dgrp * 8;
    #pragma unroll
    for (int s = 0; s < 2; ++s)
      #pragma unroll
      for (int j = 0; j < 8; ++j) {
        float f = qp[s * 32 + j];
        unsigned short h = f2bf(f);
        qfh[s][j] = (short)h;
        qfl[s][j] = (short)f2bf(f - bf2f(h));
      }
  }

  f32x4 oacc[4];
  #pragma unroll
  for (int t = 0; t < 4; ++t) oacc[t] = f32x4{0.f, 0.f, 0.f, 0.f};
  float m_r[4], l_r[4];
  #pragma unroll
  for (int j = 0; j < 4; ++j) { m_r[j] = -INFINITY; l_r[j] = 0.f; }

  for (int kb = 0; kb < S_; kb += KBLK) {
    __syncthreads();
    #pragma unroll
    for (int c = 0; c < 4; ++c) {
      int e = (c * 256 + tid) * 4;
      int r = e >> 6, col = e & 63;
      const float4 kv = *(const float4*)(Kb + (size_t)(kb + r) * D_ + col);
      ushort4 kh, kl;
      kh.x = f2bf(kv.x); kl.x = f2bf(kv.x - bf2f(kh.x));
      kh.y = f2bf(kv.y); kl.y = f2bf(kv.y - bf2f(kh.y));
      kh.z = f2bf(kv.z); kl.z = f2bf(kv.z - bf2f(kh.z));
      kh.w = f2bf(kv.w); kl.w = f2bf(kv.w - bf2f(kh.w));
      *(ushort4*)&Kh_lds[r * LDW + col] = kh;
      *(ushort4*)&Kl_lds[r * LDW + col] = kl;
      const float4 vv = *(const float4*)(Vb + (size_t)(kb + r) * D_ + col);
      Vt_lds[(col + 0) * LDW + r] = f2bf(vv.x);
      Vt_lds[(col + 1) * LDW + r] = f2bf(vv.y);
      Vt_lds[(col + 2) * LDW + r] = f2bf(vv.z);
      Vt_lds[(col + 3) * LDW + r] = f2bf(vv.w);
    }
    __syncthreads();

    f32x4 sa[4];
    #pragma unroll
    for (int t = 0; t < 4; ++t) {
      sa[t] = f32x4{0.f, 0.f, 0.f, 0.f};
      #pragma unroll
      for (int s = 0; s < 2; ++s) {
        const int off = (t * 16 + l15) * LDW + s * 32 + dgrp * 8;
        short8 kfh = *(const short8*)&Kh_lds[off];
        short8 kfl = *(const short8*)&Kl_lds[off];
        sa[t] = __builtin_amdgcn_mfma_f32_16x16x32_bf16(qfh[s], kfh, sa[t], 0, 0, 0);
        sa[t] = __builtin_amdgcn_mfma_f32_16x16x32_bf16(qfh[s], kfl, sa[t], 0, 0, 0);
        sa[t] = __builtin_amdgcn_mfma_f32_16x16x32_bf16(qfl[s], kfh, sa[t], 0, 0, 0);
      }
    }

    float pmax[4];
    #pragma unroll
    for (int j = 0; j < 4; ++j) {
      float mx = fmaxf(fmaxf(sa[0][j], sa[1][j]), fmaxf(sa[2][j], sa[3][j]));
      #pragma unroll
      for (int m = 1; m < 16; m <<= 1) mx = fmaxf(mx, __shfl_xor(mx, m));
      pmax[j] = mx;
    }
    float scale[4];
    #pragma unroll
    for (int j = 0; j < 4; ++j) {
      float nm = fmaxf(m_r[j], pmax[j]);
      scale[j] = __expf(m_r[j] - nm);
      m_r[j] = nm;
    }
    float rs[4] = {0.f, 0.f, 0.f, 0.f};
    #pragma unroll
    for (int t = 0; t < 4; ++t)
      #pragma unroll
      for (int j = 0; j < 4; ++j) {
        float p = __expf(sa[t][j] - m_r[j]);
        rs[j] += p;
        P_lds[wid][(dgrp * 4 + j) * LDW + t * 16 + l15] = f2bf(p);
      }
    #pragma unroll
    for (int j = 0; j < 4; ++j) {
      #pragma unroll
      for (int m = 1; m < 16; m <<= 1) rs[j] += __shfl_xor(rs[j], m);
      l_r[j] = l_r[j] * scale[j] + rs[j];
      #pragma unroll
      for (int t = 0; t < 4; ++t) oacc[t][j] *= scale[j];
    }

    #pragma unroll
    for (int s = 0; s < 2; ++s) {
      short8 pf = *(const short8*)&P_lds[wid][l15 * LDW + s * 32 + dgrp * 8];
      #pragma unroll
      for (int t = 0; t < 4; ++t) {
        short8 vf = *(const short8*)&Vt_lds[(t * 16 + l15) * LDW + s * 32 + dgrp * 8];
        oacc[t] = __builtin_amdgcn_mfma_f32_16x16x32_bf16(pf, vf, oacc[t], 0, 0, 0);
      }
    }
  }

  #pragma unroll
  for (int j = 0; j < 4; ++j) {
    float inv = 1.0f / l_r[j];
    int row = qtile * 64 + wid * 16 + dgrp * 4 + j;
    float* op = Ob + (size_t)row * D_ + l15;
    #pragma unroll
    for (int t = 0; t < 4; ++t)
      op[t * 16] = oacc[t][j] * inv;
  }
}

extern "C" void kernel_launch(void* const* d_in, const int* in_sizes, int n_in,
                              void* d_out, int out_size, void* d_ws, size_t ws_size,
                              hipStream_t stream) {
  const float* q = (const float*)d_in[0];
  const float* k = (const float*)d_in[1];
  const float* v = (const float*)d_in[2];
  float* o = (float*)d_out;
  const size_t PLANE = (size_t)B_ * H_ * S_ * 128;   // 16 MiB per fp16 plane
  if (ws_size >= 2 * PLANE) {
    _Float16* Kp = (_Float16*)d_ws;
    _Float16* Vt = (_Float16*)((char*)d_ws + PLANE);
    prep_k<<<8192, 256, 0, stream>>>(k, Kp);
    prep_v<<<2048, 256, 0, stream>>>(v, Vt);
    attn_fwd3<<<dim3(S_ / QBLK, B_ * H_), 256, 0, stream>>>(q, Kp, Vt, o);
  } else {
    attn_fwd<<<dim3(S_ / 64, B_ * H_), 256, 0, stream>>>(q, k, v, o);
  }
}

// Round 7
// 151.057 us; speedup vs baseline: 2.5472x; 1.4972x over previous
//
#include <hip/hip_runtime.h>
#include <hip/hip_bf16.h>
#include <stdint.h>

#define B_ 4
#define H_ 16
#define S_ 2048
#define D_ 64
#define QBLK 128
#define KBLK 64
#define LDW 72   // fallback kernel only

typedef __attribute__((ext_vector_type(8))) short short8;
typedef __attribute__((ext_vector_type(4))) float f32x4;
typedef __attribute__((ext_vector_type(16))) float f32x16;
typedef _Float16 f16x8 __attribute__((ext_vector_type(8)));
typedef _Float16 f16x4 __attribute__((ext_vector_type(4)));
typedef __fp16 fp16x2 __attribute__((ext_vector_type(2)));

__device__ __forceinline__ unsigned short f2bf(float f) {
  union { float f; unsigned int u; } x; x.f = f;
  unsigned int u = x.u;
  unsigned int r = (u + 0x7FFFu + ((u >> 16) & 1u)) >> 16;
  return (unsigned short)r;
}
__device__ __forceinline__ float bf2f(unsigned short h) {
  union { unsigned int u; float f; } y; y.u = ((unsigned int)h) << 16;
  return y.f;
}

__device__ __forceinline__ unsigned pkrtz(float a, float b) {
  union { fp16x2 h; unsigned u; } c;
  c.h = __builtin_amdgcn_cvt_pkrtz(a, b);
  return c.u;
}

// v_permlane32_swap_b32: a' = {a.lo32, b.lo32}, b' = {a.hi32, b.hi32}
__device__ __forceinline__ void swap32(unsigned &a, unsigned &b) {
#if __has_builtin(__builtin_amdgcn_permlane32_swap)
  typedef int i32x2 __attribute__((ext_vector_type(2)));
  i32x2 r = __builtin_amdgcn_permlane32_swap((int)a, (int)b, false, false);
  a = (unsigned)r[0]; b = (unsigned)r[1];
#else
  unsigned pa = (unsigned)__shfl_xor((int)a, 32);
  unsigned pb = (unsigned)__shfl_xor((int)b, 32);
  bool lo = (threadIdx.x & 32) == 0;
  unsigned r0 = lo ? a : pb;
  unsigned r1 = lo ? pa : b;
  a = r0; b = r1;
#endif
}

#define GLOAD16(g, l) __builtin_amdgcn_global_load_lds( \
    (const __attribute__((address_space(1))) unsigned int*)(g), \
    (__attribute__((address_space(3))) unsigned int*)(l), 16, 0, 0)

// ---------- prep 1: K fp32 -> swizzled fp16 plane ([S][128B] per bh) ----------
__global__ void prep_k(const float* __restrict__ K, _Float16* __restrict__ Kp) {
  int e4 = (blockIdx.x * 256 + threadIdx.x) * 4;
  int bh  = e4 >> 17;
  int rem = e4 & 131071;
  int s   = rem >> 6;
  int d0  = rem & 63;
  const float4 kv = *(const float4*)(K + (size_t)e4);
  f16x4 h;
  h[0] = (_Float16)kv.x; h[1] = (_Float16)kv.y;
  h[2] = (_Float16)kv.z; h[3] = (_Float16)kv.w;
  size_t off = ((size_t)bh * S_ + s) * 128 + (unsigned)((d0 * 2) ^ ((s & 7) << 4));
  *(f16x4*)((char*)Kp + off) = h;
}

// ---------- prep 2: V fp32 -> swizzled fp16 V^T plane ([64 d][S] per bh) ----------
__global__ void prep_v(const float* __restrict__ V, _Float16* __restrict__ Vt) {
  __shared__ _Float16 tile[64][68];
  int bh = blockIdx.x >> 5;
  int st = blockIdx.x & 31;
  const float* Vb = V + ((size_t)bh * S_ + st * 64) * 64;
  int tid = threadIdx.x;
  #pragma unroll
  for (int i = 0; i < 4; ++i) {
    int idx = i * 1024 + tid * 4;
    int r = idx >> 6, c = idx & 63;
    float4 vv = *(const float4*)(Vb + (size_t)r * 64 + c);
    f16x4 o;
    o[0] = (_Float16)vv.x; o[1] = (_Float16)vv.y;
    o[2] = (_Float16)vv.z; o[3] = (_Float16)vv.w;
    *(f16x4*)&tile[r][c] = o;
  }
  __syncthreads();
  int chunk = tid & 15;
  int dbase = tid >> 4;
  size_t outb = (size_t)bh * (64 * S_ * 2) + (size_t)st * 128;
  #pragma unroll
  for (int i = 0; i < 4; ++i) {
    int d = dbase + i * 16;
    f16x4 o;
    o[0] = tile[chunk * 4 + 0][d];
    o[1] = tile[chunk * 4 + 1][d];
    o[2] = tile[chunk * 4 + 2][d];
    o[3] = tile[chunk * 4 + 3][d];
    size_t off = outb + (size_t)d * (S_ * 2) + (unsigned)((chunk * 8) ^ ((d & 7) << 4));
    *(f16x4*)((char*)Vt + off) = o;
  }
}

// ---------- main: swapped-QK^T 32x32 MFMA, in-register softmax + P ----------
__global__ __launch_bounds__(256)
void attn_fwd4(const float* __restrict__ Q, const _Float16* __restrict__ Kg,
               const _Float16* __restrict__ Vg, float* __restrict__ O) {
  // buf0: K 8K | V 8K ; buf1: K 8K | V 8K   (epilogue reuses as 4x8K scratch)
  __shared__ char smem[32768];

  const int tid  = threadIdx.x;
  const int lane = tid & 63;
  const int wid  = tid >> 6;
  const int l31  = lane & 31;
  const int hi   = lane >> 5;

  const int qtile = blockIdx.x;
  const int bh    = blockIdx.y;

  const char* KB = (const char*)Kg + (size_t)bh * (S_ * 128);
  const char* VB = (const char*)Vg + (size_t)bh * (64 * S_ * 2);
  const float* Qb = Q + (size_t)bh * S_ * D_;
  float*       Ob = O + (size_t)bh * S_ * D_;

  // ---- Q fragments (B-operand of swapped QK^T): col=q=l31, row d = ds*16+hi*8+j
  const int qrow = qtile * QBLK + wid * 32 + l31;
  f16x8 qf[4];
  #pragma unroll
  for (int ds = 0; ds < 4; ++ds) {
    const float* qp = Qb + (size_t)qrow * D_ + ds * 16 + hi * 8;
    float4 a = *(const float4*)(qp);
    float4 b = *(const float4*)(qp + 4);
    qf[ds][0] = (_Float16)a.x; qf[ds][1] = (_Float16)a.y;
    qf[ds][2] = (_Float16)a.z; qf[ds][3] = (_Float16)a.w;
    qf[ds][4] = (_Float16)b.x; qf[ds][5] = (_Float16)b.y;
    qf[ds][6] = (_Float16)b.z; qf[ds][7] = (_Float16)b.w;
  }

  f32x16 oacc[2];   // O^T: row d = dn*32 + (reg&3)+8*(reg>>2)+4*hi, col q = l31
  #pragma unroll
  for (int dn = 0; dn < 2; ++dn)
    #pragma unroll
    for (int r = 0; r < 16; ++r) oacc[dn][r] = 0.f;
  float m_r = -INFINITY, l_r = 0.f;

  #define STAGE(buf, kb)                                                        \
    {                                                                           \
      char* Kl_ = smem + (buf) * 16384;                                         \
      char* Vl_ = Kl_ + 8192;                                                   \
      _Pragma("unroll")                                                         \
      for (int c = 0; c < 4; ++c) {                                             \
        int id = c * 4 + wid;                                                   \
        if (id < 8) {                                                           \
          GLOAD16(KB + (size_t)(kb) * 128 + id * 1024 + lane * 16,              \
                  Kl_ + id * 1024);                                             \
        } else {                                                                \
          int i = id - 8;                                                       \
          GLOAD16(VB + (size_t)(i * 8 + (lane >> 3)) * (S_ * 2)                 \
                     + ((kb) >> 6) * 128 + (lane & 7) * 16,                     \
                  Vl_ + i * 1024);                                              \
        }                                                                       \
      }                                                                         \
    }

  STAGE(0, 0);
  __syncthreads();

  for (int it = 0; it < S_ / KBLK; ++it) {
    const int cur = it & 1;
    if (it < S_ / KBLK - 1) STAGE(cur ^ 1, (it + 1) * KBLK);

    const char* Kl = smem + cur * 16384;
    const char* Vl = Kl + 8192;

    // ---- QK^T swapped: sacc[b] = S^T[k=b*32+..., q=l31]; k_local = (r&3)+4*hi+8*(r>>2)
    f32x16 sacc[2];
    #pragma unroll
    for (int b = 0; b < 2; ++b) {
      #pragma unroll
      for (int r = 0; r < 16; ++r) sacc[b][r] = 0.f;
      const int row = b * 32 + l31;
      #pragma unroll
      for (int ds = 0; ds < 4; ++ds) {
        f16x8 kf = *(const f16x8*)(Kl + row * 128 + ((ds * 32 + hi * 16) ^ ((row & 7) << 4)));
        sacc[b] = __builtin_amdgcn_mfma_f32_32x32x16_f16(kf, qf[ds], sacc[b], 0, 0, 0);
      }
    }

    // ---- in-lane softmax for row q=l31 (this lane holds 32 of 64 k; partner ^32 the rest)
    float t[16];
    #pragma unroll
    for (int r = 0; r < 16; ++r) t[r] = fmaxf(sacc[0][r], sacc[1][r]);
    #pragma unroll
    for (int s = 8; s > 0; s >>= 1)
      #pragma unroll
      for (int r = 0; r < 8; ++r)
        if (r < s) t[r] = fmaxf(t[r], t[r + s]);
    float mx = fmaxf(t[0], __shfl_xor(t[0], 32));
    float nm = fmaxf(m_r, mx);
    float sc = __expf(m_r - nm);
    m_r = nm;

    float rs0 = 0.f, rs1 = 0.f;
    #pragma unroll
    for (int b = 0; b < 2; ++b)
      #pragma unroll
      for (int r = 0; r < 16; ++r) {
        float p = __expf(sacc[b][r] - nm);
        sacc[b][r] = p;
        if (r & 1) rs1 += p; else rs0 += p;
      }
    float rs = rs0 + rs1;
    rs += __shfl_xor(rs, 32);
    l_r = l_r * sc + rs;
    #pragma unroll
    for (int dn = 0; dn < 2; ++dn)
      #pragma unroll
      for (int r = 0; r < 16; ++r) oacc[dn][r] *= sc;

    // ---- pack P to fp16 words: ww[b][r1*2+0] = {k=8r1+4hi+0,1}, +1 = {+2,+3}
    unsigned ww[2][8];
    #pragma unroll
    for (int b = 0; b < 2; ++b)
      #pragma unroll
      for (int r1 = 0; r1 < 4; ++r1) {
        ww[b][r1 * 2 + 0] = pkrtz(sacc[b][4 * r1 + 0], sacc[b][4 * r1 + 1]);
        ww[b][r1 * 2 + 1] = pkrtz(sacc[b][4 * r1 + 2], sacc[b][4 * r1 + 3]);
      }

    // ---- P^T B-frags via permlane32_swap: pb[ks] rows k = ks*16 + hi*8 + j
    f16x8 pb[4];
    #pragma unroll
    for (int ks = 0; ks < 4; ++ks) {
      const int b = ks >> 1, e = (ks & 1) * 2;
      unsigned u0 = ww[b][e * 2 + 0];        // w[e]
      unsigned u1 = ww[b][e * 2 + 1];        // w'[e]
      unsigned u2 = ww[b][(e + 1) * 2 + 0];  // w[e+1]
      unsigned u3 = ww[b][(e + 1) * 2 + 1];  // w'[e+1]
      swap32(u0, u2);   // u0 -> word0 (k+0,1), u2 -> word2 (k+4,5)
      swap32(u1, u3);   // u1 -> word1 (k+2,3), u3 -> word3 (k+6,7)
      union { unsigned u[4]; f16x8 v; } c;
      c.u[0] = u0; c.u[1] = u1; c.u[2] = u2; c.u[3] = u3;
      pb[ks] = c.v;
    }

    // ---- PV: O^T[d, q] += V^T[d, k] * P^T[k, q]
    #pragma unroll
    for (int dn = 0; dn < 2; ++dn) {
      const int d = dn * 32 + l31;
      #pragma unroll
      for (int ks = 0; ks < 4; ++ks) {
        f16x8 vf = *(const f16x8*)(Vl + d * 128 + ((ks * 32 + hi * 16) ^ ((d & 7) << 4)));
        oacc[dn] = __builtin_amdgcn_mfma_f32_32x32x16_f16(vf, pb[ks], oacc[dn], 0, 0, 0);
      }
    }
    __syncthreads();   // drains prefetch vmcnt + protects LDS reuse
  }
  #undef STAGE

  // ---- epilogue: O^T -> LDS (per-wave 8KB) -> coalesced O stores ----
  const float inv = 1.0f / l_r;
  float* Ep = (float*)(smem + wid * 8192);   // [64 d][32 q]
  #pragma unroll
  for (int dn = 0; dn < 2; ++dn)
    #pragma unroll
    for (int r = 0; r < 16; ++r) {
      int d = dn * 32 + (r & 3) + 8 * (r >> 2) + 4 * hi;
      Ep[d * 32 + l31] = oacc[dn][r] * inv;
    }
  __syncthreads();
  const int q2 = lane >> 1, dh = lane & 1;
  float* orow = Ob + (size_t)(qtile * QBLK + wid * 32 + q2) * D_ + dh * 32;
  #pragma unroll
  for (int c = 0; c < 8; ++c) {
    float4 o4;
    o4.x = Ep[(dh * 32 + c * 4 + 0) * 32 + q2];
    o4.y = Ep[(dh * 32 + c * 4 + 1) * 32 + q2];
    o4.z = Ep[(dh * 32 + c * 4 + 2) * 32 + q2];
    o4.w = Ep[(dh * 32 + c * 4 + 3) * 32 + q2];
    *(float4*)(orow + c * 4) = o4;
  }
}

// ---------- fallback (round-3 double-bf16 kernel, used only if ws too small) ----------
__global__ __launch_bounds__(256, 2)
void attn_fwd(const float* __restrict__ Q, const float* __restrict__ K,
              const float* __restrict__ V, float* __restrict__ O) {
  __shared__ alignas(16) unsigned short Kh_lds[KBLK * LDW];
  __shared__ alignas(16) unsigned short Kl_lds[KBLK * LDW];
  __shared__ alignas(16) unsigned short Vt_lds[D_ * LDW];
  __shared__ alignas(16) unsigned short P_lds[4][16 * LDW];

  const int tid  = threadIdx.x;
  const int lane = tid & 63;
  const int wid  = tid >> 6;
  const int l15  = lane & 15;
  const int dgrp = lane >> 4;

  const int qtile = blockIdx.x;
  const int bh    = blockIdx.y;

  const size_t base = (size_t)bh * S_ * D_;
  const float* Qb = Q + base;
  const float* Kb = K + base;
  const float* Vb = V + base;
  float*       Ob = O + base;

  const int qrow = qtile * 64 + wid * 16 + l15;
  short8 qfh[2], qfl[2];
  {
    const float* qp = Qb + (size_t)qrow * D_ + dgrp * 8;
    #pragma unroll
    for (int s = 0; s < 2; ++s)
      #pragma unroll
      for (int j = 0; j < 8; ++j) {
        float f = qp[s * 32 + j];
        unsigned short h = f2bf(f);
        qfh[s][j] = (short)h;
        qfl[s][j] = (short)f2bf(f - bf2f(h));
      }
  }

  f32x4 oacc[4];
  #pragma unroll
  for (int t = 0; t < 4; ++t) oacc[t] = f32x4{0.f, 0.f, 0.f, 0.f};
  float m_r[4], l_r[4];
  #pragma unroll
  for (int j = 0; j < 4; ++j) { m_r[j] = -INFINITY; l_r[j] = 0.f; }

  for (int kb = 0; kb < S_; kb += KBLK) {
    __syncthreads();
    #pragma unroll
    for (int c = 0; c < 4; ++c) {
      int e = (c * 256 + tid) * 4;
      int r = e >> 6, col = e & 63;
      const float4 kv = *(const float4*)(Kb + (size_t)(kb + r) * D_ + col);
      ushort4 kh, kl;
      kh.x = f2bf(kv.x); kl.x = f2bf(kv.x - bf2f(kh.x));
      kh.y = f2bf(kv.y); kl.y = f2bf(kv.y - bf2f(kh.y));
      kh.z = f2bf(kv.z); kl.z = f2bf(kv.z - bf2f(kh.z));
      kh.w = f2bf(kv.w); kl.w = f2bf(kv.w - bf2f(kh.w));
      *(ushort4*)&Kh_lds[r * LDW + col] = kh;
      *(ushort4*)&Kl_lds[r * LDW + col] = kl;
      const float4 vv = *(const float4*)(Vb + (size_t)(kb + r) * D_ + col);
      Vt_lds[(col + 0) * LDW + r] = f2bf(vv.x);
      Vt_lds[(col + 1) * LDW + r] = f2bf(vv.y);
      Vt_lds[(col + 2) * LDW + r] = f2bf(vv.z);
      Vt_lds[(col + 3) * LDW + r] = f2bf(vv.w);
    }
    __syncthreads();

    f32x4 sa[4];
    #pragma unroll
    for (int t = 0; t < 4; ++t) {
      sa[t] = f32x4{0.f, 0.f, 0.f, 0.f};
      #pragma unroll
      for (int s = 0; s < 2; ++s) {
        const int off = (t * 16 + l15) * LDW + s * 32 + dgrp * 8;
        short8 kfh = *(const short8*)&Kh_lds[off];
        short8 kfl = *(const short8*)&Kl_lds[off];
        sa[t] = __builtin_amdgcn_mfma_f32_16x16x32_bf16(qfh[s], kfh, sa[t], 0, 0, 0);
        sa[t] = __builtin_amdgcn_mfma_f32_16x16x32_bf16(qfh[s], kfl, sa[t], 0, 0, 0);
        sa[t] = __builtin_amdgcn_mfma_f32_16x16x32_bf16(qfl[s], kfh, sa[t], 0, 0, 0);
      }
    }

    float pmax[4];
    #pragma unroll
    for (int j = 0; j < 4; ++j) {
      float mx = fmaxf(fmaxf(sa[0][j], sa[1][j]), fmaxf(sa[2][j], sa[3][j]));
      #pragma unroll
      for (int m = 1; m < 16; m <<= 1) mx = fmaxf(mx, __shfl_xor(mx, m));
      pmax[j] = mx;
    }
    float scale[4];
    #pragma unroll
    for (int j = 0; j < 4; ++j) {
      float nm = fmaxf(m_r[j], pmax[j]);
      scale[j] = __expf(m_r[j] - nm);
      m_r[j] = nm;
    }
    float rs[4] = {0.f, 0.f, 0.f, 0.f};
    #pragma unroll
    for (int t = 0; t < 4; ++t)
      #pragma unroll
      for (int j = 0; j < 4; ++j) {
        float p = __expf(sa[t][j] - m_r[j]);
        rs[j] += p;
        P_lds[wid][(dgrp * 4 + j) * LDW + t * 16 + l15] = f2bf(p);
      }
    #pragma unroll
    for (int j = 0; j < 4; ++j) {
      #pragma unroll
      for (int m = 1; m < 16; m <<= 1) rs[j] += __shfl_xor(rs[j], m);
      l_r[j] = l_r[j] * scale[j] + rs[j];
      #pragma unroll
      for (int t = 0; t < 4; ++t) oacc[t][j] *= scale[j];
    }

    #pragma unroll
    for (int s = 0; s < 2; ++s) {
      short8 pf = *(const short8*)&P_lds[wid][l15 * LDW + s * 32 + dgrp * 8];
      #pragma unroll
      for (int t = 0; t < 4; ++t) {
        short8 vf = *(const short8*)&Vt_lds[(t * 16 + l15) * LDW + s * 32 + dgrp * 8];
        oacc[t] = __builtin_amdgcn_mfma_f32_16x16x32_bf16(pf, vf, oacc[t], 0, 0, 0);
      }
    }
  }

  #pragma unroll
  for (int j = 0; j < 4; ++j) {
    float inv = 1.0f / l_r[j];
    int row = qtile * 64 + wid * 16 + dgrp * 4 + j;
    float* op = Ob + (size_t)row * D_ + l15;
    #pragma unroll
    for (int t = 0; t < 4; ++t)
      op[t * 16] = oacc[t][j] * inv;
  }
}

extern "C" void kernel_launch(void* const* d_in, const int* in_sizes, int n_in,
                              void* d_out, int out_size, void* d_ws, size_t ws_size,
                              hipStream_t stream) {
  const float* q = (const float*)d_in[0];
  const float* k = (const float*)d_in[1];
  const float* v = (const float*)d_in[2];
  float* o = (float*)d_out;
  const size_t PLANE = (size_t)B_ * H_ * S_ * 128;   // 16 MiB per fp16 plane
  if (ws_size >= 2 * PLANE) {
    _Float16* Kp = (_Float16*)d_ws;
    _Float16* Vt = (_Float16*)((char*)d_ws + PLANE);
    prep_k<<<8192, 256, 0, stream>>>(k, Kp);
    prep_v<<<2048, 256, 0, stream>>>(v, Vt);
    attn_fwd4<<<dim3(S_ / QBLK, B_ * H_), 256, 0, stream>>>(q, Kp, Vt, o);
  } else {
    attn_fwd<<<dim3(S_ / 64, B_ * H_), 256, 0, stream>>>(q, k, v, o);
  }
}

// Round 8
// 145.440 us; speedup vs baseline: 2.6456x; 1.0386x over previous
//
#include <hip/hip_runtime.h>
#include <hip/hip_bf16.h>
#include <stdint.h>

#define B_ 4
#define H_ 16
#define S_ 2048
#define D_ 64
#define QBLK 128
#define KBLK 64
#define LDW 72   // fallback kernel only
#define LOG2E 1.44269504088896340736f

typedef __attribute__((ext_vector_type(8))) short short8;
typedef __attribute__((ext_vector_type(4))) float f32x4;
typedef __attribute__((ext_vector_type(16))) float f32x16;
typedef _Float16 f16x8 __attribute__((ext_vector_type(8)));
typedef _Float16 f16x4 __attribute__((ext_vector_type(4)));
typedef __fp16 fp16x2 __attribute__((ext_vector_type(2)));

__device__ __forceinline__ unsigned short f2bf(float f) {
  union { float f; unsigned int u; } x; x.f = f;
  unsigned int u = x.u;
  unsigned int r = (u + 0x7FFFu + ((u >> 16) & 1u)) >> 16;
  return (unsigned short)r;
}
__device__ __forceinline__ float bf2f(unsigned short h) {
  union { unsigned int u; float f; } y; y.u = ((unsigned int)h) << 16;
  return y.f;
}

__device__ __forceinline__ unsigned pkrtz(float a, float b) {
  union { fp16x2 h; unsigned u; } c;
  c.h = __builtin_amdgcn_cvt_pkrtz(a, b);
  return c.u;
}
__device__ __forceinline__ fp16x2 u2h(unsigned u) {
  union { unsigned u; fp16x2 h; } c; c.u = u; return c.h;
}

__device__ __forceinline__ float fast_exp2(float x) {
#if __has_builtin(__builtin_amdgcn_exp2f)
  return __builtin_amdgcn_exp2f(x);
#else
  return exp2f(x);
#endif
}

// v_permlane32_swap_b32: a'[L<32]=a[L], a'[L>=32]=b[L-32]; b'[L<32]=a[L+32], b'[L>=32]=b[L]
__device__ __forceinline__ void swap32(unsigned &a, unsigned &b) {
#if __has_builtin(__builtin_amdgcn_permlane32_swap)
  typedef int i32x2 __attribute__((ext_vector_type(2)));
  i32x2 r = __builtin_amdgcn_permlane32_swap((int)a, (int)b, false, false);
  a = (unsigned)r[0]; b = (unsigned)r[1];
#else
  unsigned pa = (unsigned)__shfl_xor((int)a, 32);
  unsigned pb = (unsigned)__shfl_xor((int)b, 32);
  bool lo = (threadIdx.x & 32) == 0;
  unsigned r0 = lo ? a : pb;
  unsigned r1 = lo ? pa : b;
  a = r0; b = r1;
#endif
}

__device__ __forceinline__ float pairmax(float x) {
  unsigned a = __float_as_uint(x), b = a;
  swap32(a, b);
  return fmaxf(__uint_as_float(a), __uint_as_float(b));
}
__device__ __forceinline__ float pairsum(float x) {
  unsigned a = __float_as_uint(x), b = a;
  swap32(a, b);
  return __uint_as_float(a) + __uint_as_float(b);
}

#define GLOAD16(g, l) __builtin_amdgcn_global_load_lds( \
    (const __attribute__((address_space(1))) unsigned int*)(g), \
    (__attribute__((address_space(3))) unsigned int*)(l), 16, 0, 0)

// ---------- prep 1: K fp32 -> swizzled fp16 plane ([S][128B] per bh) ----------
__global__ void prep_k(const float* __restrict__ K, _Float16* __restrict__ Kp) {
  int e4 = (blockIdx.x * 256 + threadIdx.x) * 4;
  int bh  = e4 >> 17;
  int rem = e4 & 131071;
  int s   = rem >> 6;
  int d0  = rem & 63;
  const float4 kv = *(const float4*)(K + (size_t)e4);
  f16x4 h;
  h[0] = (_Float16)kv.x; h[1] = (_Float16)kv.y;
  h[2] = (_Float16)kv.z; h[3] = (_Float16)kv.w;
  size_t off = ((size_t)bh * S_ + s) * 128 + (unsigned)((d0 * 2) ^ ((s & 7) << 4));
  *(f16x4*)((char*)Kp + off) = h;
}

// ---------- prep 2: V fp32 -> swizzled fp16 V^T plane ([64 d][S] per bh) ----------
__global__ void prep_v(const float* __restrict__ V, _Float16* __restrict__ Vt) {
  __shared__ _Float16 tile[64][68];
  int bh = blockIdx.x >> 5;
  int st = blockIdx.x & 31;
  const float* Vb = V + ((size_t)bh * S_ + st * 64) * 64;
  int tid = threadIdx.x;
  #pragma unroll
  for (int i = 0; i < 4; ++i) {
    int idx = i * 1024 + tid * 4;
    int r = idx >> 6, c = idx & 63;
    float4 vv = *(const float4*)(Vb + (size_t)r * 64 + c);
    f16x4 o;
    o[0] = (_Float16)vv.x; o[1] = (_Float16)vv.y;
    o[2] = (_Float16)vv.z; o[3] = (_Float16)vv.w;
    *(f16x4*)&tile[r][c] = o;
  }
  __syncthreads();
  int chunk = tid & 15;
  int dbase = tid >> 4;
  size_t outb = (size_t)bh * (64 * S_ * 2) + (size_t)st * 128;
  #pragma unroll
  for (int i = 0; i < 4; ++i) {
    int d = dbase + i * 16;
    f16x4 o;
    o[0] = tile[chunk * 4 + 0][d];
    o[1] = tile[chunk * 4 + 1][d];
    o[2] = tile[chunk * 4 + 2][d];
    o[3] = tile[chunk * 4 + 3][d];
    size_t off = outb + (size_t)d * (S_ * 2) + (unsigned)((chunk * 8) ^ ((d & 7) << 4));
    *(f16x4*)((char*)Vt + off) = o;
  }
}

// ---------- main: swapped-QK^T 32x32 MFMA, exp2-domain in-register softmax ----------
__global__ __launch_bounds__(256)
void attn_fwd4(const float* __restrict__ Q, const _Float16* __restrict__ Kg,
               const _Float16* __restrict__ Vg, float* __restrict__ O) {
  // buf0: K 8K | V 8K ; buf1: K 8K | V 8K   (epilogue reuses as 4x8K scratch)
  __shared__ char smem[32768];

  const int tid  = threadIdx.x;
  const int lane = tid & 63;
  const int wid  = tid >> 6;
  const int l31  = lane & 31;
  const int hi   = lane >> 5;

  const int qtile = blockIdx.x;
  const int bh    = blockIdx.y;

  const char* KB = (const char*)Kg + (size_t)bh * (S_ * 128);
  const char* VB = (const char*)Vg + (size_t)bh * (64 * S_ * 2);
  const float* Qb = Q + (size_t)bh * S_ * D_;
  float*       Ob = O + (size_t)bh * S_ * D_;

  // ---- Q fragments (B-operand of swapped QK^T), pre-scaled by log2(e):
  //      col=q=l31, row d = ds*16+hi*8+j
  const int qrow = qtile * QBLK + wid * 32 + l31;
  f16x8 qf[4];
  #pragma unroll
  for (int ds = 0; ds < 4; ++ds) {
    const float* qp = Qb + (size_t)qrow * D_ + ds * 16 + hi * 8;
    float4 a = *(const float4*)(qp);
    float4 b = *(const float4*)(qp + 4);
    qf[ds][0] = (_Float16)(a.x * LOG2E); qf[ds][1] = (_Float16)(a.y * LOG2E);
    qf[ds][2] = (_Float16)(a.z * LOG2E); qf[ds][3] = (_Float16)(a.w * LOG2E);
    qf[ds][4] = (_Float16)(b.x * LOG2E); qf[ds][5] = (_Float16)(b.y * LOG2E);
    qf[ds][6] = (_Float16)(b.z * LOG2E); qf[ds][7] = (_Float16)(b.w * LOG2E);
  }

  f32x16 oacc[2];   // O^T: row d = dn*32 + (reg&3)+8*(reg>>2)+4*hi, col q = l31
  #pragma unroll
  for (int dn = 0; dn < 2; ++dn)
    #pragma unroll
    for (int r = 0; r < 16; ++r) oacc[dn][r] = 0.f;
  float m_r = -INFINITY, l_r = 0.f;

  #define STAGE(buf, kb)                                                        \
    {                                                                           \
      char* Kl_ = smem + (buf) * 16384;                                         \
      char* Vl_ = Kl_ + 8192;                                                   \
      _Pragma("unroll")                                                         \
      for (int c = 0; c < 4; ++c) {                                             \
        int id = c * 4 + wid;                                                   \
        if (id < 8) {                                                           \
          GLOAD16(KB + (size_t)(kb) * 128 + id * 1024 + lane * 16,              \
                  Kl_ + id * 1024);                                             \
        } else {                                                                \
          int i = id - 8;                                                       \
          GLOAD16(VB + (size_t)(i * 8 + (lane >> 3)) * (S_ * 2)                 \
                     + ((kb) >> 6) * 128 + (lane & 7) * 16,                     \
                  Vl_ + i * 1024);                                              \
        }                                                                       \
      }                                                                         \
    }

  STAGE(0, 0);
  __syncthreads();

  for (int it = 0; it < S_ / KBLK; ++it) {
    const int cur = it & 1;
    if (it < S_ / KBLK - 1) STAGE(cur ^ 1, (it + 1) * KBLK);

    const char* Kl = smem + cur * 16384;
    const char* Vl = Kl + 8192;

    // ---- QK^T swapped (log2 domain): sacc[b] = S^T[k=b*32+..., q=l31]
    //      k_local = (r&3)+4*hi+8*(r>>2)
    f32x16 sacc[2];
    __builtin_amdgcn_s_setprio(1);
    #pragma unroll
    for (int b = 0; b < 2; ++b) {
      #pragma unroll
      for (int r = 0; r < 16; ++r) sacc[b][r] = 0.f;
      const int row = b * 32 + l31;
      #pragma unroll
      for (int ds = 0; ds < 4; ++ds) {
        f16x8 kf = *(const f16x8*)(Kl + row * 128 + ((ds * 32 + hi * 16) ^ ((row & 7) << 4)));
        sacc[b] = __builtin_amdgcn_mfma_f32_32x32x16_f16(kf, qf[ds], sacc[b], 0, 0, 0);
      }
    }
    __builtin_amdgcn_s_setprio(0);

    // ---- row max (max3-friendly tree), cross-half via permlane ----
    float u[16];
    #pragma unroll
    for (int r = 0; r < 16; ++r) u[r] = fmaxf(sacc[0][r], sacc[1][r]);
    float w0 = fmaxf(fmaxf(u[0], u[1]), u[2]);
    float w1 = fmaxf(fmaxf(u[3], u[4]), u[5]);
    float w2 = fmaxf(fmaxf(u[6], u[7]), u[8]);
    float w3 = fmaxf(fmaxf(u[9], u[10]), u[11]);
    float w4 = fmaxf(fmaxf(u[12], u[13]), u[14]);
    float x0 = fmaxf(fmaxf(w0, w1), w2);
    float x1 = fmaxf(fmaxf(w3, w4), u[15]);
    float mx = pairmax(fmaxf(x0, x1));

    // ---- defer-max (T13, THR=8 in log2 units): skip rescale unless max grew ----
    if (!__all(mx <= m_r + 8.f)) {
      float nm = fmaxf(m_r, mx);
      float sc = fast_exp2(m_r - nm);
      m_r = nm;
      l_r *= sc;
      #pragma unroll
      for (int dn = 0; dn < 2; ++dn)
        #pragma unroll
        for (int r = 0; r < 16; ++r) oacc[dn][r] *= sc;
    }

    // ---- P = 2^(s - m): exp2 + pack to fp16 words
    //      ww[b][r1*2+0] = {k=8r1+4hi+0,1}, +1 = {+2,+3}
    unsigned ww[2][8];
#if !__has_builtin(__builtin_amdgcn_fdot2)
    float rs0 = 0.f, rs1 = 0.f;
#endif
    #pragma unroll
    for (int b = 0; b < 2; ++b)
      #pragma unroll
      for (int r1 = 0; r1 < 4; ++r1) {
        float p0 = fast_exp2(sacc[b][4 * r1 + 0] - m_r);
        float p1 = fast_exp2(sacc[b][4 * r1 + 1] - m_r);
        float p2 = fast_exp2(sacc[b][4 * r1 + 2] - m_r);
        float p3 = fast_exp2(sacc[b][4 * r1 + 3] - m_r);
        ww[b][r1 * 2 + 0] = pkrtz(p0, p1);
        ww[b][r1 * 2 + 1] = pkrtz(p2, p3);
#if !__has_builtin(__builtin_amdgcn_fdot2)
        rs0 += p0 + p2; rs1 += p1 + p3;
#endif
      }

    // ---- row sum from packed fp16 (consistent with PV numerator) ----
    float rs;
#if __has_builtin(__builtin_amdgcn_fdot2)
    {
      const fp16x2 ones = {(__fp16)1.f, (__fp16)1.f};
      float rA = 0.f, rB = 0.f, rC = 0.f, rD = 0.f;
      #pragma unroll
      for (int b = 0; b < 2; ++b) {
        rA = __builtin_amdgcn_fdot2(u2h(ww[b][0]), ones, rA, false);
        rB = __builtin_amdgcn_fdot2(u2h(ww[b][1]), ones, rB, false);
        rC = __builtin_amdgcn_fdot2(u2h(ww[b][2]), ones, rC, false);
        rD = __builtin_amdgcn_fdot2(u2h(ww[b][3]), ones, rD, false);
        rA = __builtin_amdgcn_fdot2(u2h(ww[b][4]), ones, rA, false);
        rB = __builtin_amdgcn_fdot2(u2h(ww[b][5]), ones, rB, false);
        rC = __builtin_amdgcn_fdot2(u2h(ww[b][6]), ones, rC, false);
        rD = __builtin_amdgcn_fdot2(u2h(ww[b][7]), ones, rD, false);
      }
      rs = (rA + rB) + (rC + rD);
    }
#else
    rs = rs0 + rs1;
#endif
    l_r += pairsum(rs);

    // ---- P^T B-frags via permlane32_swap: pb[ks] rows k = ks*16 + hi*8 + j
    f16x8 pb[4];
    #pragma unroll
    for (int ks = 0; ks < 4; ++ks) {
      const int b = ks >> 1, e = (ks & 1) * 2;
      unsigned u0 = ww[b][e * 2 + 0];
      unsigned u1 = ww[b][e * 2 + 1];
      unsigned u2 = ww[b][(e + 1) * 2 + 0];
      unsigned u3 = ww[b][(e + 1) * 2 + 1];
      swap32(u0, u2);
      swap32(u1, u3);
      union { unsigned u[4]; f16x8 v; } c;
      c.u[0] = u0; c.u[1] = u1; c.u[2] = u2; c.u[3] = u3;
      pb[ks] = c.v;
    }

    // ---- PV: O^T[d, q] += V^T[d, k] * P^T[k, q]
    __builtin_amdgcn_s_setprio(1);
    #pragma unroll
    for (int dn = 0; dn < 2; ++dn) {
      const int d = dn * 32 + l31;
      #pragma unroll
      for (int ks = 0; ks < 4; ++ks) {
        f16x8 vf = *(const f16x8*)(Vl + d * 128 + ((ks * 32 + hi * 16) ^ ((d & 7) << 4)));
        oacc[dn] = __builtin_amdgcn_mfma_f32_32x32x16_f16(vf, pb[ks], oacc[dn], 0, 0, 0);
      }
    }
    __builtin_amdgcn_s_setprio(0);
    __syncthreads();   // drains prefetch vmcnt + protects LDS reuse
  }
  #undef STAGE

  // ---- epilogue: O^T -> LDS (per-wave 8KB) -> coalesced O stores ----
  const float inv = 1.0f / l_r;
  float* Ep = (float*)(smem + wid * 8192);   // [64 d][32 q]
  #pragma unroll
  for (int dn = 0; dn < 2; ++dn)
    #pragma unroll
    for (int r = 0; r < 16; ++r) {
      int d = dn * 32 + (r & 3) + 8 * (r >> 2) + 4 * hi;
      Ep[d * 32 + l31] = oacc[dn][r] * inv;
    }
  __syncthreads();
  const int q2 = lane >> 1, dh = lane & 1;
  float* orow = Ob + (size_t)(qtile * QBLK + wid * 32 + q2) * D_ + dh * 32;
  #pragma unroll
  for (int c = 0; c < 8; ++c) {
    float4 o4;
    o4.x = Ep[(dh * 32 + c * 4 + 0) * 32 + q2];
    o4.y = Ep[(dh * 32 + c * 4 + 1) * 32 + q2];
    o4.z = Ep[(dh * 32 + c * 4 + 2) * 32 + q2];
    o4.w = Ep[(dh * 32 + c * 4 + 3) * 32 + q2];
    *(float4*)(orow + c * 4) = o4;
  }
}

// ---------- fallback (round-3 double-bf16 kernel, used only if ws too small) ----------
__global__ __launch_bounds__(256, 2)
void attn_fwd(const float* __restrict__ Q, const float* __restrict__ K,
              const float* __restrict__ V, float* __restrict__ O) {
  __shared__ alignas(16) unsigned short Kh_lds[KBLK * LDW];
  __shared__ alignas(16) unsigned short Kl_lds[KBLK * LDW];
  __shared__ alignas(16) unsigned short Vt_lds[D_ * LDW];
  __shared__ alignas(16) unsigned short P_lds[4][16 * LDW];

  const int tid  = threadIdx.x;
  const int lane = tid & 63;
  const int wid  = tid >> 6;
  const int l15  = lane & 15;
  const int dgrp = lane >> 4;

  const int qtile = blockIdx.x;
  const int bh    = blockIdx.y;

  const size_t base = (size_t)bh * S_ * D_;
  const float* Qb = Q + base;
  const float* Kb = K + base;
  const float* Vb = V + base;
  float*       Ob = O + base;

  const int qrow = qtile * 64 + wid * 16 + l15;
  short8 qfh[2], qfl[2];
  {
    const float* qp = Qb + (size_t)qrow * D_ + dgrp * 8;
    #pragma unroll
    for (int s = 0; s < 2; ++s)
      #pragma unroll
      for (int j = 0; j < 8; ++j) {
        float f = qp[s * 32 + j];
        unsigned short h = f2bf(f);
        qfh[s][j] = (short)h;
        qfl[s][j] = (short)f2bf(f - bf2f(h));
      }
  }

  f32x4 oacc[4];
  #pragma unroll
  for (int t = 0; t < 4; ++t) oacc[t] = f32x4{0.f, 0.f, 0.f, 0.f};
  float m_r[4], l_r[4];
  #pragma unroll
  for (int j = 0; j < 4; ++j) { m_r[j] = -INFINITY; l_r[j] = 0.f; }

  for (int kb = 0; kb < S_; kb += KBLK) {
    __syncthreads();
    #pragma unroll
    for (int c = 0; c < 4; ++c) {
      int e = (c * 256 + tid) * 4;
      int r = e >> 6, col = e & 63;
      const float4 kv = *(const float4*)(Kb + (size_t)(kb + r) * D_ + col);
      ushort4 kh, kl;
      kh.x = f2bf(kv.x); kl.x = f2bf(kv.x - bf2f(kh.x));
      kh.y = f2bf(kv.y); kl.y = f2bf(kv.y - bf2f(kh.y));
      kh.z = f2bf(kv.z); kl.z = f2bf(kv.z - bf2f(kh.z));
      kh.w = f2bf(kv.w); kl.w = f2bf(kv.w - bf2f(kh.w));
      *(ushort4*)&Kh_lds[r * LDW + col] = kh;
      *(ushort4*)&Kl_lds[r * LDW + col] = kl;
      const float4 vv = *(const float4*)(Vb + (size_t)(kb + r) * D_ + col);
      Vt_lds[(col + 0) * LDW + r] = f2bf(vv.x);
      Vt_lds[(col + 1) * LDW + r] = f2bf(vv.y);
      Vt_lds[(col + 2) * LDW + r] = f2bf(vv.z);
      Vt_lds[(col + 3) * LDW + r] = f2bf(vv.w);
    }
    __syncthreads();

    f32x4 sa[4];
    #pragma unroll
    for (int t = 0; t < 4; ++t) {
      sa[t] = f32x4{0.f, 0.f, 0.f, 0.f};
      #pragma unroll
      for (int s = 0; s < 2; ++s) {
        const int off = (t * 16 + l15) * LDW + s * 32 + dgrp * 8;
        short8 kfh = *(const short8*)&Kh_lds[off];
        short8 kfl = *(const short8*)&Kl_lds[off];
        sa[t] = __builtin_amdgcn_mfma_f32_16x16x32_bf16(qfh[s], kfh, sa[t], 0, 0, 0);
        sa[t] = __builtin_amdgcn_mfma_f32_16x16x32_bf16(qfh[s], kfl, sa[t], 0, 0, 0);
        sa[t] = __builtin_amdgcn_mfma_f32_16x16x32_bf16(qfl[s], kfh, sa[t], 0, 0, 0);
      }
    }

    float pmax[4];
    #pragma unroll
    for (int j = 0; j < 4; ++j) {
      float mx = fmaxf(fmaxf(sa[0][j], sa[1][j]), fmaxf(sa[2][j], sa[3][j]));
      #pragma unroll
      for (int m = 1; m < 16; m <<= 1) mx = fmaxf(mx, __shfl_xor(mx, m));
      pmax[j] = mx;
    }
    float scale[4];
    #pragma unroll
    for (int j = 0; j < 4; ++j) {
      float nm = fmaxf(m_r[j], pmax[j]);
      scale[j] = __expf(m_r[j] - nm);
      m_r[j] = nm;
    }
    float rs[4] = {0.f, 0.f, 0.f, 0.f};
    #pragma unroll
    for (int t = 0; t < 4; ++t)
      #pragma unroll
      for (int j = 0; j < 4; ++j) {
        float p = __expf(sa[t][j] - m_r[j]);
        rs[j] += p;
        P_lds[wid][(dgrp * 4 + j) * LDW + t * 16 + l15] = f2bf(p);
      }
    #pragma unroll
    for (int j = 0; j < 4; ++j) {
      #pragma unroll
      for (int m = 1; m < 16; m <<= 1) rs[j] += __shfl_xor(rs[j], m);
      l_r[j] = l_r[j] * scale[j] + rs[j];
      #pragma unroll
      for (int t = 0; t < 4; ++t) oacc[t][j] *= scale[j];
    }

    #pragma unroll
    for (int s = 0; s < 2; ++s) {
      short8 pf = *(const short8*)&P_lds[wid][l15 * LDW + s * 32 + dgrp * 8];
      #pragma unroll
      for (int t = 0; t < 4; ++t) {
        short8 vf = *(const short8*)&Vt_lds[(t * 16 + l15) * LDW + s * 32 + dgrp * 8];
        oacc[t] = __builtin_amdgcn_mfma_f32_16x16x32_bf16(pf, vf, oacc[t], 0, 0, 0);
      }
    }
  }

  #pragma unroll
  for (int j = 0; j < 4; ++j) {
    float inv = 1.0f / l_r[j];
    int row = qtile * 64 + wid * 16 + dgrp * 4 + j;
    float* op = Ob + (size_t)row * D_ + l15;
    #pragma unroll
    for (int t = 0; t < 4; ++t)
      op[t * 16] = oacc[t][j] * inv;
  }
}

extern "C" void kernel_launch(void* const* d_in, const int* in_sizes, int n_in,
                              void* d_out, int out_size, void* d_ws, size_t ws_size,
                              hipStream_t stream) {
  const float* q = (const float*)d_in[0];
  const float* k = (const float*)d_in[1];
  const float* v = (const float*)d_in[2];
  float* o = (float*)d_out;
  const size_t PLANE = (size_t)B_ * H_ * S_ * 128;   // 16 MiB per fp16 plane
  if (ws_size >= 2 * PLANE) {
    _Float16* Kp = (_Float16*)d_ws;
    _Float16* Vt = (_Float16*)((char*)d_ws + PLANE);
    prep_k<<<8192, 256, 0, stream>>>(k, Kp);
    prep_v<<<2048, 256, 0, stream>>>(v, Vt);
    attn_fwd4<<<dim3(S_ / QBLK, B_ * H_), 256, 0, stream>>>(q, Kp, Vt, o);
  } else {
    attn_fwd<<<dim3(S_ / 64, B_ * H_), 256, 0, stream>>>(q, k, v, o);
  }
}

// Round 9
// 144.772 us; speedup vs baseline: 2.6578x; 1.0046x over previous
//
#include <hip/hip_runtime.h>
#include <hip/hip_bf16.h>
#include <stdint.h>

#define B_ 4
#define H_ 16
#define S_ 2048
#define D_ 64
#define QBLK 128
#define KBLK 64
#define LDW 72   // fallback kernel only
#define LOG2E 1.44269504088896340736f

typedef __attribute__((ext_vector_type(8))) short short8;
typedef __attribute__((ext_vector_type(4))) float f32x4;
typedef __attribute__((ext_vector_type(16))) float f32x16;
typedef _Float16 f16x8 __attribute__((ext_vector_type(8)));
typedef _Float16 f16x4 __attribute__((ext_vector_type(4)));
typedef __fp16 fp16x2 __attribute__((ext_vector_type(2)));

__device__ __forceinline__ unsigned short f2bf(float f) {
  union { float f; unsigned int u; } x; x.f = f;
  unsigned int u = x.u;
  unsigned int r = (u + 0x7FFFu + ((u >> 16) & 1u)) >> 16;
  return (unsigned short)r;
}
__device__ __forceinline__ float bf2f(unsigned short h) {
  union { unsigned int u; float f; } y; y.u = ((unsigned int)h) << 16;
  return y.f;
}

__device__ __forceinline__ unsigned pkrtz(float a, float b) {
  union { fp16x2 h; unsigned u; } c;
  c.h = __builtin_amdgcn_cvt_pkrtz(a, b);
  return c.u;
}
__device__ __forceinline__ fp16x2 u2h(unsigned u) {
  union { unsigned u; fp16x2 h; } c; c.u = u; return c.h;
}

__device__ __forceinline__ float fast_exp2(float x) {
#if __has_builtin(__builtin_amdgcn_exp2f)
  return __builtin_amdgcn_exp2f(x);
#else
  return exp2f(x);
#endif
}

// v_permlane32_swap_b32: a'[L<32]=a[L], a'[L>=32]=b[L-32]; b'[L<32]=a[L+32], b'[L>=32]=b[L]
__device__ __forceinline__ void swap32(unsigned &a, unsigned &b) {
#if __has_builtin(__builtin_amdgcn_permlane32_swap)
  typedef int i32x2 __attribute__((ext_vector_type(2)));
  i32x2 r = __builtin_amdgcn_permlane32_swap((int)a, (int)b, false, false);
  a = (unsigned)r[0]; b = (unsigned)r[1];
#else
  unsigned pa = (unsigned)__shfl_xor((int)a, 32);
  unsigned pb = (unsigned)__shfl_xor((int)b, 32);
  bool lo = (threadIdx.x & 32) == 0;
  unsigned r0 = lo ? a : pb;
  unsigned r1 = lo ? pa : b;
  a = r0; b = r1;
#endif
}

__device__ __forceinline__ float pairmax(float x) {
  unsigned a = __float_as_uint(x), b = a;
  swap32(a, b);
  return fmaxf(__uint_as_float(a), __uint_as_float(b));
}
__device__ __forceinline__ float pairsum(float x) {
  unsigned a = __float_as_uint(x), b = a;
  swap32(a, b);
  return __uint_as_float(a) + __uint_as_float(b);
}

#define GLOAD16(g, l) __builtin_amdgcn_global_load_lds( \
    (const __attribute__((address_space(1))) unsigned int*)(g), \
    (__attribute__((address_space(3))) unsigned int*)(l), 16, 0, 0)

// ---------- prep 1: K fp32 -> swizzled fp16 plane ([S][128B] per bh) ----------
__global__ void prep_k(const float* __restrict__ K, _Float16* __restrict__ Kp) {
  int e4 = (blockIdx.x * 256 + threadIdx.x) * 4;
  int bh  = e4 >> 17;
  int rem = e4 & 131071;
  int s   = rem >> 6;
  int d0  = rem & 63;
  const float4 kv = *(const float4*)(K + (size_t)e4);
  f16x4 h;
  h[0] = (_Float16)kv.x; h[1] = (_Float16)kv.y;
  h[2] = (_Float16)kv.z; h[3] = (_Float16)kv.w;
  size_t off = ((size_t)bh * S_ + s) * 128 + (unsigned)((d0 * 2) ^ ((s & 7) << 4));
  *(f16x4*)((char*)Kp + off) = h;
}

// ---------- prep 2: V fp32 -> swizzled fp16 V^T plane ([64 d][S] per bh) ----------
__global__ void prep_v(const float* __restrict__ V, _Float16* __restrict__ Vt) {
  __shared__ _Float16 tile[64][66];   // stride 33 words -> conflict-free column reads
  int bh = blockIdx.x >> 5;
  int st = blockIdx.x & 31;
  const float* Vb = V + ((size_t)bh * S_ + st * 64) * 64;
  int tid = threadIdx.x;
  #pragma unroll
  for (int i = 0; i < 4; ++i) {
    int idx = i * 1024 + tid * 4;
    int r = idx >> 6, c = idx & 63;
    float4 vv = *(const float4*)(Vb + (size_t)r * 64 + c);
    f16x4 o;
    o[0] = (_Float16)vv.x; o[1] = (_Float16)vv.y;
    o[2] = (_Float16)vv.z; o[3] = (_Float16)vv.w;
    *(f16x4*)&tile[r][c] = o;
  }
  __syncthreads();
  int chunk = tid & 15;
  int dbase = tid >> 4;
  size_t outb = (size_t)bh * (64 * S_ * 2) + (size_t)st * 128;
  #pragma unroll
  for (int i = 0; i < 4; ++i) {
    int d = dbase + i * 16;
    f16x4 o;
    o[0] = tile[chunk * 4 + 0][d];
    o[1] = tile[chunk * 4 + 1][d];
    o[2] = tile[chunk * 4 + 2][d];
    o[3] = tile[chunk * 4 + 3][d];
    size_t off = outb + (size_t)d * (S_ * 2) + (unsigned)((chunk * 8) ^ ((d & 7) << 4));
    *(f16x4*)((char*)Vt + off) = o;
  }
}

// ---------- main: swapped-QK^T 32x32 MFMA, split-half pipelined softmax ----------
__global__ __launch_bounds__(256)
void attn_fwd4(const float* __restrict__ Q, const _Float16* __restrict__ Kg,
               const _Float16* __restrict__ Vg, float* __restrict__ O) {
  // buf0: K 8K | V 8K ; buf1: K 8K | V 8K   (epilogue reuses as 4x8K scratch)
  __shared__ char smem[32768];

  const int tid  = threadIdx.x;
  const int lane = tid & 63;
  const int wid  = tid >> 6;
  const int l31  = lane & 31;
  const int hi   = lane >> 5;

  const int qtile = blockIdx.x;
  const int bh    = blockIdx.y;

  const char* KB = (const char*)Kg + (size_t)bh * (S_ * 128);
  const char* VB = (const char*)Vg + (size_t)bh * (64 * S_ * 2);
  const float* Qb = Q + (size_t)bh * S_ * D_;
  float*       Ob = O + (size_t)bh * S_ * D_;

  // ---- Q fragments (B-operand of swapped QK^T), pre-scaled by log2(e):
  //      col=q=l31, row d = ds*16+hi*8+j
  const int qrow = qtile * QBLK + wid * 32 + l31;
  f16x8 qf[4];
  #pragma unroll
  for (int ds = 0; ds < 4; ++ds) {
    const float* qp = Qb + (size_t)qrow * D_ + ds * 16 + hi * 8;
    float4 a = *(const float4*)(qp);
    float4 b = *(const float4*)(qp + 4);
    qf[ds][0] = (_Float16)(a.x * LOG2E); qf[ds][1] = (_Float16)(a.y * LOG2E);
    qf[ds][2] = (_Float16)(a.z * LOG2E); qf[ds][3] = (_Float16)(a.w * LOG2E);
    qf[ds][4] = (_Float16)(b.x * LOG2E); qf[ds][5] = (_Float16)(b.y * LOG2E);
    qf[ds][6] = (_Float16)(b.z * LOG2E); qf[ds][7] = (_Float16)(b.w * LOG2E);
  }

  f32x16 oacc[2];   // O^T: row d = dn*32 + (reg&3)+8*(reg>>2)+4*hi, col q = l31
  #pragma unroll
  for (int dn = 0; dn < 2; ++dn)
    #pragma unroll
    for (int r = 0; r < 16; ++r) oacc[dn][r] = 0.f;
  float m_r = -INFINITY, l_r = 0.f;   // l_r is LANE-LOCAL partial; pairsum in epilogue

  // loop-invariant zero C-operand: kills 32 v_mov/iter of acc zero-init
  f32x16 zero16;
  #pragma unroll
  for (int r = 0; r < 16; ++r) zero16[r] = 0.f;

  #define STAGE(buf, kb)                                                        \
    {                                                                           \
      char* Kl_ = smem + (buf) * 16384;                                         \
      char* Vl_ = Kl_ + 8192;                                                   \
      _Pragma("unroll")                                                         \
      for (int c = 0; c < 4; ++c) {                                             \
        int id = c * 4 + wid;                                                   \
        if (id < 8) {                                                           \
          GLOAD16(KB + (size_t)(kb) * 128 + id * 1024 + lane * 16,              \
                  Kl_ + id * 1024);                                             \
        } else {                                                                \
          int i = id - 8;                                                       \
          GLOAD16(VB + (size_t)(i * 8 + (lane >> 3)) * (S_ * 2)                 \
                     + ((kb) >> 6) * 128 + (lane & 7) * 16,                     \
                  Vl_ + i * 1024);                                              \
        }                                                                       \
      }                                                                         \
    }

  STAGE(0, 0);
  __syncthreads();

  for (int it = 0; it < S_ / KBLK; ++it) {
    const int cur = it & 1;
    if (it < S_ / KBLK - 1) STAGE(cur ^ 1, (it + 1) * KBLK);

    const char* Kl = smem + cur * 16384;
    const char* Vl = Kl + 8192;

    // ---- QK^T both halves issued first (MFMA executes under softmax VALU) ----
    f32x16 sacc_a, sacc_b;
    __builtin_amdgcn_s_setprio(1);
    {
      const int row = l31;
      const int sw = (row & 7) << 4;
      sacc_a = __builtin_amdgcn_mfma_f32_32x32x16_f16(
          *(const f16x8*)(Kl + row * 128 + ((0) ^ sw)), qf[0], zero16, 0, 0, 0);
      sacc_a = __builtin_amdgcn_mfma_f32_32x32x16_f16(
          *(const f16x8*)(Kl + row * 128 + ((32 + hi * 16) ^ sw) - hi * 16 + hi * 16), qf[1], sacc_a, 0, 0, 0);
      sacc_a = __builtin_amdgcn_mfma_f32_32x32x16_f16(
          *(const f16x8*)(Kl + row * 128 + ((64 + hi * 16) ^ sw) - hi * 16 + hi * 16), qf[2], sacc_a, 0, 0, 0);
      sacc_a = __builtin_amdgcn_mfma_f32_32x32x16_f16(
          *(const f16x8*)(Kl + row * 128 + ((96 + hi * 16) ^ sw) - hi * 16 + hi * 16), qf[3], sacc_a, 0, 0, 0);
    }
    __builtin_amdgcn_s_setprio(0);
    // NOTE: the hi*16 terms above must be inside the XOR; rewrite cleanly:
    {
      const int row = l31;
      const int sw = (row & 7) << 4;
      sacc_a = __builtin_amdgcn_mfma_f32_32x32x16_f16(
          *(const f16x8*)(Kl + row * 128 + ((0 * 32 + hi * 16) ^ sw)), qf[0], zero16, 0, 0, 0);
      #pragma unroll
      for (int ds = 1; ds < 4; ++ds)
        sacc_a = __builtin_amdgcn_mfma_f32_32x32x16_f16(
            *(const f16x8*)(Kl + row * 128 + ((ds * 32 + hi * 16) ^ sw)), qf[ds], sacc_a, 0, 0, 0);
    }
    {
      const int row = 32 + l31;
      const int sw = (row & 7) << 4;
      sacc_b = __builtin_amdgcn_mfma_f32_32x32x16_f16(
          *(const f16x8*)(Kl + row * 128 + ((0 * 32 + hi * 16) ^ sw)), qf[0], zero16, 0, 0, 0);
      #pragma unroll
      for (int ds = 1; ds < 4; ++ds)
        sacc_b = __builtin_amdgcn_mfma_f32_32x32x16_f16(
            *(const f16x8*)(Kl + row * 128 + ((ds * 32 + hi * 16) ^ sw)), qf[ds], sacc_b, 0, 0, 0);
    }

    // ================= half A: keys [0,32) =================
    {
      float v0 = fmaxf(fmaxf(sacc_a[0], sacc_a[1]), sacc_a[2]);
      float v1 = fmaxf(fmaxf(sacc_a[3], sacc_a[4]), sacc_a[5]);
      float v2 = fmaxf(fmaxf(sacc_a[6], sacc_a[7]), sacc_a[8]);
      float v3 = fmaxf(fmaxf(sacc_a[9], sacc_a[10]), sacc_a[11]);
      float v4 = fmaxf(fmaxf(sacc_a[12], sacc_a[13]), sacc_a[14]);
      float w0 = fmaxf(fmaxf(v0, v1), v2);
      float w1 = fmaxf(fmaxf(v3, v4), sacc_a[15]);
      float mx = pairmax(fmaxf(w0, w1));
      if (!__all(mx <= m_r + 8.f)) {
        float nm = fmaxf(m_r, mx);
        float sc = fast_exp2(m_r - nm);
        m_r = nm; l_r *= sc;
        #pragma unroll
        for (int dn = 0; dn < 2; ++dn)
          #pragma unroll
          for (int r = 0; r < 16; ++r) oacc[dn][r] *= sc;
      }
      unsigned ww[8];
      #pragma unroll
      for (int r1 = 0; r1 < 4; ++r1) {
        float p0 = fast_exp2(sacc_a[4 * r1 + 0] - m_r);
        float p1 = fast_exp2(sacc_a[4 * r1 + 1] - m_r);
        float p2 = fast_exp2(sacc_a[4 * r1 + 2] - m_r);
        float p3 = fast_exp2(sacc_a[4 * r1 + 3] - m_r);
        ww[r1 * 2 + 0] = pkrtz(p0, p1);
        ww[r1 * 2 + 1] = pkrtz(p2, p3);
      }
      {
        const fp16x2 ones = {(__fp16)1.f, (__fp16)1.f};
        float rA = __builtin_amdgcn_fdot2(u2h(ww[0]), ones, 0.f, false);
        float rB = __builtin_amdgcn_fdot2(u2h(ww[1]), ones, 0.f, false);
        rA = __builtin_amdgcn_fdot2(u2h(ww[2]), ones, rA, false);
        rB = __builtin_amdgcn_fdot2(u2h(ww[3]), ones, rB, false);
        rA = __builtin_amdgcn_fdot2(u2h(ww[4]), ones, rA, false);
        rB = __builtin_amdgcn_fdot2(u2h(ww[5]), ones, rB, false);
        rA = __builtin_amdgcn_fdot2(u2h(ww[6]), ones, rA, false);
        rB = __builtin_amdgcn_fdot2(u2h(ww[7]), ones, rB, false);
        l_r += rA + rB;
      }
      f16x8 pb0, pb1;
      {
        unsigned u0 = ww[0], u1 = ww[1], u2 = ww[2], u3 = ww[3];
        swap32(u0, u2); swap32(u1, u3);
        union { unsigned u[4]; f16x8 v; } c;
        c.u[0] = u0; c.u[1] = u1; c.u[2] = u2; c.u[3] = u3;
        pb0 = c.v;
      }
      {
        unsigned u0 = ww[4], u1 = ww[5], u2 = ww[6], u3 = ww[7];
        swap32(u0, u2); swap32(u1, u3);
        union { unsigned u[4]; f16x8 v; } c;
        c.u[0] = u0; c.u[1] = u1; c.u[2] = u2; c.u[3] = u3;
        pb1 = c.v;
      }
      __builtin_amdgcn_s_setprio(1);
      #pragma unroll
      for (int dn = 0; dn < 2; ++dn) {
        const int d = dn * 32 + l31;
        const int sw = (d & 7) << 4;
        f16x8 vf0 = *(const f16x8*)(Vl + d * 128 + ((0 * 32 + hi * 16) ^ sw));
        f16x8 vf1 = *(const f16x8*)(Vl + d * 128 + ((1 * 32 + hi * 16) ^ sw));
        oacc[dn] = __builtin_amdgcn_mfma_f32_32x32x16_f16(vf0, pb0, oacc[dn], 0, 0, 0);
        oacc[dn] = __builtin_amdgcn_mfma_f32_32x32x16_f16(vf1, pb1, oacc[dn], 0, 0, 0);
      }
      __builtin_amdgcn_s_setprio(0);
    }

    // ================= half B: keys [32,64) =================
    {
      float v0 = fmaxf(fmaxf(sacc_b[0], sacc_b[1]), sacc_b[2]);
      float v1 = fmaxf(fmaxf(sacc_b[3], sacc_b[4]), sacc_b[5]);
      float v2 = fmaxf(fmaxf(sacc_b[6], sacc_b[7]), sacc_b[8]);
      float v3 = fmaxf(fmaxf(sacc_b[9], sacc_b[10]), sacc_b[11]);
      float v4 = fmaxf(fmaxf(sacc_b[12], sacc_b[13]), sacc_b[14]);
      float w0 = fmaxf(fmaxf(v0, v1), v2);
      float w1 = fmaxf(fmaxf(v3, v4), sacc_b[15]);
      float mx = pairmax(fmaxf(w0, w1));
      if (!__all(mx <= m_r + 8.f)) {
        float nm = fmaxf(m_r, mx);
        float sc = fast_exp2(m_r - nm);
        m_r = nm; l_r *= sc;
        #pragma unroll
        for (int dn = 0; dn < 2; ++dn)
          #pragma unroll
          for (int r = 0; r < 16; ++r) oacc[dn][r] *= sc;
      }
      unsigned ww[8];
      #pragma unroll
      for (int r1 = 0; r1 < 4; ++r1) {
        float p0 = fast_exp2(sacc_b[4 * r1 + 0] - m_r);
        float p1 = fast_exp2(sacc_b[4 * r1 + 1] - m_r);
        float p2 = fast_exp2(sacc_b[4 * r1 + 2] - m_r);
        float p3 = fast_exp2(sacc_b[4 * r1 + 3] - m_r);
        ww[r1 * 2 + 0] = pkrtz(p0, p1);
        ww[r1 * 2 + 1] = pkrtz(p2, p3);
      }
      {
        const fp16x2 ones = {(__fp16)1.f, (__fp16)1.f};
        float rA = __builtin_amdgcn_fdot2(u2h(ww[0]), ones, 0.f, false);
        float rB = __builtin_amdgcn_fdot2(u2h(ww[1]), ones, 0.f, false);
        rA = __builtin_amdgcn_fdot2(u2h(ww[2]), ones, rA, false);
        rB = __builtin_amdgcn_fdot2(u2h(ww[3]), ones, rB, false);
        rA = __builtin_amdgcn_fdot2(u2h(ww[4]), ones, rA, false);
        rB = __builtin_amdgcn_fdot2(u2h(ww[5]), ones, rB, false);
        rA = __builtin_amdgcn_fdot2(u2h(ww[6]), ones, rA, false);
        rB = __builtin_amdgcn_fdot2(u2h(ww[7]), ones, rB, false);
        l_r += rA + rB;
      }
      f16x8 pb2, pb3;
      {
        unsigned u0 = ww[0], u1 = ww[1], u2 = ww[2], u3 = ww[3];
        swap32(u0, u2); swap32(u1, u3);
        union { unsigned u[4]; f16x8 v; } c;
        c.u[0] = u0; c.u[1] = u1; c.u[2] = u2; c.u[3] = u3;
        pb2 = c.v;
      }
      {
        unsigned u0 = ww[4], u1 = ww[5], u2 = ww[6], u3 = ww[7];
        swap32(u0, u2); swap32(u1, u3);
        union { unsigned u[4]; f16x8 v; } c;
        c.u[0] = u0; c.u[1] = u1; c.u[2] = u2; c.u[3] = u3;
        pb3 = c.v;
      }
      __builtin_amdgcn_s_setprio(1);
      #pragma unroll
      for (int dn = 0; dn < 2; ++dn) {
        const int d = dn * 32 + l31;
        const int sw = (d & 7) << 4;
        f16x8 vf2 = *(const f16x8*)(Vl + d * 128 + ((2 * 32 + hi * 16) ^ sw));
        f16x8 vf3 = *(const f16x8*)(Vl + d * 128 + ((3 * 32 + hi * 16) ^ sw));
        oacc[dn] = __builtin_amdgcn_mfma_f32_32x32x16_f16(vf2, pb2, oacc[dn], 0, 0, 0);
        oacc[dn] = __builtin_amdgcn_mfma_f32_32x32x16_f16(vf3, pb3, oacc[dn], 0, 0, 0);
      }
      __builtin_amdgcn_s_setprio(0);
    }

    __syncthreads();   // drains prefetch vmcnt + protects LDS reuse
  }
  #undef STAGE

  // ---- epilogue: O^T -> LDS (per-wave 8KB) -> coalesced O stores ----
  const float inv = 1.0f / pairsum(l_r);
  float* Ep = (float*)(smem + wid * 8192);   // [64 d][32 q]
  #pragma unroll
  for (int dn = 0; dn < 2; ++dn)
    #pragma unroll
    for (int r = 0; r < 16; ++r) {
      int d = dn * 32 + (r & 3) + 8 * (r >> 2) + 4 * hi;
      Ep[d * 32 + l31] = oacc[dn][r] * inv;
    }
  __syncthreads();
  const int q2 = lane >> 1, dh = lane & 1;
  float* orow = Ob + (size_t)(qtile * QBLK + wid * 32 + q2) * D_ + dh * 32;
  #pragma unroll
  for (int c = 0; c < 8; ++c) {
    float4 o4;
    o4.x = Ep[(dh * 32 + c * 4 + 0) * 32 + q2];
    o4.y = Ep[(dh * 32 + c * 4 + 1) * 32 + q2];
    o4.z = Ep[(dh * 32 + c * 4 + 2) * 32 + q2];
    o4.w = Ep[(dh * 32 + c * 4 + 3) * 32 + q2];
    *(float4*)(orow + c * 4) = o4;
  }
}

// ---------- fallback (round-3 double-bf16 kernel, used only if ws too small) ----------
__global__ __launch_bounds__(256, 2)
void attn_fwd(const float* __restrict__ Q, const float* __restrict__ K,
              const float* __restrict__ V, float* __restrict__ O) {
  __shared__ alignas(16) unsigned short Kh_lds[KBLK * LDW];
  __shared__ alignas(16) unsigned short Kl_lds[KBLK * LDW];
  __shared__ alignas(16) unsigned short Vt_lds[D_ * LDW];
  __shared__ alignas(16) unsigned short P_lds[4][16 * LDW];

  const int tid  = threadIdx.x;
  const int lane = tid & 63;
  const int wid  = tid >> 6;
  const int l15  = lane & 15;
  const int dgrp = lane >> 4;

  const int qtile = blockIdx.x;
  const int bh    = blockIdx.y;

  const size_t base = (size_t)bh * S_ * D_;
  const float* Qb = Q + base;
  const float* Kb = K + base;
  const float* Vb = V + base;
  float*       Ob = O + base;

  const int qrow = qtile * 64 + wid * 16 + l15;
  short8 qfh[2], qfl[2];
  {
    const float* qp = Qb + (size_t)qrow * D_ + dgrp * 8;
    #pragma unroll
    for (int s = 0; s < 2; ++s)
      #pragma unroll
      for (int j = 0; j < 8; ++j) {
        float f = qp[s * 32 + j];
        unsigned short h = f2bf(f);
        qfh[s][j] = (short)h;
        qfl[s][j] = (short)f2bf(f - bf2f(h));
      }
  }

  f32x4 oacc[4];
  #pragma unroll
  for (int t = 0; t < 4; ++t) oacc[t] = f32x4{0.f, 0.f, 0.f, 0.f};
  float m_r[4], l_r[4];
  #pragma unroll
  for (int j = 0; j < 4; ++j) { m_r[j] = -INFINITY; l_r[j] = 0.f; }

  for (int kb = 0; kb < S_; kb += KBLK) {
    __syncthreads();
    #pragma unroll
    for (int c = 0; c < 4; ++c) {
      int e = (c * 256 + tid) * 4;
      int r = e >> 6, col = e & 63;
      const float4 kv = *(const float4*)(Kb + (size_t)(kb + r) * D_ + col);
      ushort4 kh, kl;
      kh.x = f2bf(kv.x); kl.x = f2bf(kv.x - bf2f(kh.x));
      kh.y = f2bf(kv.y); kl.y = f2bf(kv.y - bf2f(kh.y));
      kh.z = f2bf(kv.z); kl.z = f2bf(kv.z - bf2f(kh.z));
      kh.w = f2bf(kv.w); kl.w = f2bf(kv.w - bf2f(kh.w));
      *(ushort4*)&Kh_lds[r * LDW + col] = kh;
      *(ushort4*)&Kl_lds[r * LDW + col] = kl;
      const float4 vv = *(const float4*)(Vb + (size_t)(kb + r) * D_ + col);
      Vt_lds[(col + 0) * LDW + r] = f2bf(vv.x);
      Vt_lds[(col + 1) * LDW + r] = f2bf(vv.y);
      Vt_lds[(col + 2) * LDW + r] = f2bf(vv.z);
      Vt_lds[(col + 3) * LDW + r] = f2bf(vv.w);
    }
    __syncthreads();

    f32x4 sa[4];
    #pragma unroll
    for (int t = 0; t < 4; ++t) {
      sa[t] = f32x4{0.f, 0.f, 0.f, 0.f};
      #pragma unroll
      for (int s = 0; s < 2; ++s) {
        const int off = (t * 16 + l15) * LDW + s * 32 + dgrp * 8;
        short8 kfh = *(const short8*)&Kh_lds[off];
        short8 kfl = *(const short8*)&Kl_lds[off];
        sa[t] = __builtin_amdgcn_mfma_f32_16x16x32_bf16(qfh[s], kfh, sa[t], 0, 0, 0);
        sa[t] = __builtin_amdgcn_mfma_f32_16x16x32_bf16(qfh[s], kfl, sa[t], 0, 0, 0);
        sa[t] = __builtin_amdgcn_mfma_f32_16x16x32_bf16(qfl[s], kfh, sa[t], 0, 0, 0);
      }
    }

    float pmax[4];
    #pragma unroll
    for (int j = 0; j < 4; ++j) {
      float mx = fmaxf(fmaxf(sa[0][j], sa[1][j]), fmaxf(sa[2][j], sa[3][j]));
      #pragma unroll
      for (int m = 1; m < 16; m <<= 1) mx = fmaxf(mx, __shfl_xor(mx, m));
      pmax[j] = mx;
    }
    float scale[4];
    #pragma unroll
    for (int j = 0; j < 4; ++j) {
      float nm = fmaxf(m_r[j], pmax[j]);
      scale[j] = __expf(m_r[j] - nm);
      m_r[j] = nm;
    }
    float rs[4] = {0.f, 0.f, 0.f, 0.f};
    #pragma unroll
    for (int t = 0; t < 4; ++t)
      #pragma unroll
      for (int j = 0; j < 4; ++j) {
        float p = __expf(sa[t][j] - m_r[j]);
        rs[j] += p;
        P_lds[wid][(dgrp * 4 + j) * LDW + t * 16 + l15] = f2bf(p);
      }
    #pragma unroll
    for (int j = 0; j < 4; ++j) {
      #pragma unroll
      for (int m = 1; m < 16; m <<= 1) rs[j] += __shfl_xor(rs[j], m);
      l_r[j] = l_r[j] * scale[j] + rs[j];
      #pragma unroll
      for (int t = 0; t < 4; ++t) oacc[t][j] *= scale[j];
    }

    #pragma unroll
    for (int s = 0; s < 2; ++s) {
      short8 pf = *(const short8*)&P_lds[wid][l15 * LDW + s * 32 + dgrp * 8];
      #pragma unroll
      for (int t = 0; t < 4; ++t) {
        short8 vf = *(const short8*)&Vt_lds[(t * 16 + l15) * LDW + s * 32 + dgrp * 8];
        oacc[t] = __builtin_amdgcn_mfma_f32_16x16x32_bf16(pf, vf, oacc[t], 0, 0, 0);
      }
    }
  }

  #pragma unroll
  for (int j = 0; j < 4; ++j) {
    float inv = 1.0f / l_r[j];
    int row = qtile * 64 + wid * 16 + dgrp * 4 + j;
    float* op = Ob + (size_t)row * D_ + l15;
    #pragma unroll
    for (int t = 0; t < 4; ++t)
      op[t * 16] = oacc[t][j] * inv;
  }
}

extern "C" void kernel_launch(void* const* d_in, const int* in_sizes, int n_in,
                              void* d_out, int out_size, void* d_ws, size_t ws_size,
                              hipStream_t stream) {
  const float* q = (const float*)d_in[0];
  const float* k = (const float*)d_in[1];
  const float* v = (const float*)d_in[2];
  float* o = (float*)d_out;
  const size_t PLANE = (size_t)B_ * H_ * S_ * 128;   // 16 MiB per fp16 plane
  if (ws_size >= 2 * PLANE) {
    _Float16* Kp = (_Float16*)d_ws;
    _Float16* Vt = (_Float16*)((char*)d_ws + PLANE);
    prep_k<<<8192, 256, 0, stream>>>(k, Kp);
    prep_v<<<2048, 256, 0, stream>>>(v, Vt);
    attn_fwd4<<<dim3(S_ / QBLK, B_ * H_), 256, 0, stream>>>(q, Kp, Vt, o);
  } else {
    attn_fwd<<<dim3(S_ / 64, B_ * H_), 256, 0, stream>>>(q, k, v, o);
  }
}